// Round 1
// 456.494 us; speedup vs baseline: 1.0225x; 1.0225x over previous
//
#include <hip/hip_runtime.h>

typedef unsigned short u16;
typedef short bf16x8 __attribute__((ext_vector_type(8)));
typedef float f32x4 __attribute__((ext_vector_type(4)));

#define BB 2
#define TT 1024
#define DD 768
#define HH 12
#define HD 64
#define FFD 3072
#define NE 4
#define NTOK (BB*TT)
// compact MoE row space: sum_e ceil(cnt[e]/128)*128 <= 4096 + 4*127 = 4604
#define CROWS 4608
#define SLABZ 3538944L   // CROWS*DD elements per FF2 partial slab

#define MFMA16(a, b, c) __builtin_amdgcn_mfma_f32_16x16x32_bf16((a), (b), (c), 0, 0, 0)

#define ASYNC16(gsrc, ldst)                                                    \
    __builtin_amdgcn_global_load_lds(                                          \
        (const __attribute__((address_space(1))) void*)(gsrc),                 \
        (__attribute__((address_space(3))) void*)(ldst), 16, 0, 0)

__device__ __forceinline__ float us2f(u16 u) {
    return __uint_as_float(((unsigned int)u) << 16);
}
__device__ __forceinline__ u16 f2us(float f) {
    unsigned int x = __float_as_uint(f);
    x += 0x7fffu + ((x >> 16) & 1u);
    return (u16)(x >> 16);
}

// ---------------------------------------------------------------------------
// Flat fp32 -> bf16 convert. n8 = n/8 work items.
// ---------------------------------------------------------------------------
__global__ __launch_bounds__(256) void convert_kernel(
    const float* __restrict__ in, u16* __restrict__ out, int n8)
{
    int i = blockIdx.x * 256 + threadIdx.x;
    if (i >= n8) return;
    const float4* p = reinterpret_cast<const float4*>(in) + (size_t)i * 2;
    float4 a = p[0], b = p[1];
    u16 o[8] = {f2us(a.x), f2us(a.y), f2us(a.z), f2us(a.w),
                f2us(b.x), f2us(b.y), f2us(b.z), f2us(b.w)};
    *reinterpret_cast<uint4*>(out + (size_t)i * 8) = *reinterpret_cast<uint4*>(o);
}

// ---------------------------------------------------------------------------
// Transpose + convert (vectorized): per z, src [.,C] fp32 -> dst bf16 with
// dst[c*dstStride + r]. float4 reads, uint2 (4xbf16) packed writes.
// ---------------------------------------------------------------------------
__global__ __launch_bounds__(256) void transpose_convert_kernel(
    const float* __restrict__ src, u16* __restrict__ dst,
    int C, int dstStride, long srcZ, long dstZ)
{
    __shared__ float tile[32][33];
    const float* s = src + (size_t)blockIdx.z * srcZ;
    u16* d = dst + (size_t)blockIdx.z * dstZ;
    const int c0 = blockIdx.x * 32, r0 = blockIdx.y * 32;
    const int tid = threadIdx.x;
    {
        const int r = tid >> 3, cs = (tid & 7) * 4;
        float4 v = *reinterpret_cast<const float4*>(&s[(size_t)(r0 + r) * C + c0 + cs]);
        tile[r][cs] = v.x; tile[r][cs + 1] = v.y;
        tile[r][cs + 2] = v.z; tile[r][cs + 3] = v.w;
    }
    __syncthreads();
    {
        const int c = tid >> 3, rs = (tid & 7) * 4;
        u16 o[4] = {f2us(tile[rs][c]), f2us(tile[rs + 1][c]),
                    f2us(tile[rs + 2][c]), f2us(tile[rs + 3][c])};
        *reinterpret_cast<uint2*>(&d[(size_t)(c0 + c) * dstStride + r0 + rs]) =
            *reinterpret_cast<uint2*>(o);
    }
}

// ---------------------------------------------------------------------------
// Zero per-expert counters + compact row->token map (padding rows stay 0 ->
// they gather token 0: valid reads, outputs never consumed).
// ---------------------------------------------------------------------------
__global__ __launch_bounds__(256) void zero_kernel(
    int* __restrict__ cnt, int* __restrict__ rowtok)
{
    const int tid = threadIdx.x;
    if (tid < NE) cnt[tid] = 0;
    for (int i = tid; i < CROWS; i += 256) rowtok[i] = 0;
}

// ---------------------------------------------------------------------------
// After gate: compute per-expert 128-padded base offsets (prefix over cnt)
// and fill rowtok (compact row -> token) + tok2row (token -> its 2 rows).
// ---------------------------------------------------------------------------
__global__ __launch_bounds__(256) void build_kernel(
    const int* __restrict__ cnt, const int* __restrict__ eslot,
    int* __restrict__ rowtok, int* __restrict__ tok2row)
{
    const int t = blockIdx.x * 256 + threadIdx.x;
    if (t >= NTOK) return;
    const int p0 = (cnt[0] + 127) & ~127;
    const int p1 = (cnt[1] + 127) & ~127;
    const int p2 = (cnt[2] + 127) & ~127;
    #pragma unroll
    for (int i = 0; i < 2; i++) {
        const int v = eslot[t * 2 + i];
        const int e = v >> 16, s = v & 0xffff;
        const int base = (e > 0 ? p0 : 0) + (e > 1 ? p1 : 0) + (e > 2 ? p2 : 0);
        const int crow = base + s;
        rowtok[crow] = t;
        tok2row[t * 2 + i] = crow;
    }
}

// ---------------------------------------------------------------------------
// bf16 MFMA GEMM: C[M,N] = A[M,K] * Bt[N,K]^T  (both row-major, K-contiguous)
// 128x128 tile, 4 waves, 16x16x32 MFMA, fp32 accum.
// Staging: global_load_lds 16B into unpadded [128][32] u16 LDS; XOR column-
// group swizzle at the global-source side (bank-balanced, conflict-free).
// modes:
//  0 QKV:  y=acc+biasF[n]; bf16 scatter: Q,K -> [B,H,T,64]; V -> VT [B,H,64,T]
//  2 FF1 (COMPACT): A-rows gathered via rowtok[baseE + tilerow]; active iff
//          by*128 < cnt[e]; y=relu(acc+b1[e,n])*comb[tok,e] -> hb[crow][FFD]
//          via LDS-repacked dwordx4 stores
//  3 Wo split-K partial: outF + z*cZ, plain fp32 store
//  4 FF2 (COMPACT): A=hb compact rows (baseE folded into Ab), B=W2T expert
//          slab + k-slice z; partial fp32 -> pslab + z*cZ at compact rows
// swz (XCD-aware flat-grid decode; fid%8 assumed = XCD):
//  0: 3D grid as-is
//  1: FF1 flat 1536: xcd=fid&7; r=fid>>3; ne=xcd*12+(r%12); by=r/12 (mt);
//     bx=ne%24 (n); e=ne/24   -> each XCD owns 12 (n,e) B-tiles (L2-resident)
//  3: FF2 flat 1536: xcd=fid&7; r=fid>>3; half=r>=96; ez=xcd*2+half;
//     e=ez>>2; z=ez&3; rr=r-96*half; bx=rr%6; by=rr/6
//     -> each XCD owns two (e,z) B-slices (1.18MB each, L2-resident)
// ---------------------------------------------------------------------------
__global__ __launch_bounds__(256) void gemm_bt_kernel(
    const u16* __restrict__ A, int lda, long aZ,
    const u16* __restrict__ Bt, int ldb, long bZ,
    int K, int mode, int swz,
    float* __restrict__ outF, u16* __restrict__ outH,
    u16* __restrict__ outH2, u16* __restrict__ outH3,
    int ldc, long cZ,
    const float* __restrict__ biasF, int biasZ,
    const int* __restrict__ rowtok, const int* __restrict__ cntp,
    const float* __restrict__ comb)
{
    __shared__ __align__(16) u16 As[128 * 32];
    __shared__ __align__(16) u16 Bs[128 * 32];
    const int tid = threadIdx.x;
    int bx, by, z, e = 0, baseE = 0;
    if (swz == 3) {
        const int fid = blockIdx.x;
        const int xcd = fid & 7; int r = fid >> 3;
        const int half = (r >= 96) ? 1 : 0; r -= half * 96;
        bx = r % 6; by = r / 6;
        const int ez = xcd * 2 + half; e = ez >> 2; z = ez & 3;
    } else if (swz == 1) {
        const int fid = blockIdx.x;
        const int xcd = fid & 7; const int r = fid >> 3;
        const int ne = xcd * 12 + (r % 12);
        by = r / 12; bx = ne % 24; e = ne / 24; z = e;
    } else {
        bx = blockIdx.x; by = blockIdx.y; z = blockIdx.z;
    }
    if (mode == 2 || mode == 4) {
        const int q0 = (cntp[0] + 127) & ~127;
        const int q1 = (cntp[1] + 127) & ~127;
        const int q2 = (cntp[2] + 127) & ~127;
        baseE = (e > 0 ? q0 : 0) + (e > 1 ? q1 : 0) + (e > 2 ? q2 : 0);
        if (by * 128 >= cntp[e]) return;   // uniform per block: safe early-exit
    }
    const int m0 = by * 128, n0 = bx * 128;
    const u16* Ab = A + (size_t)z * aZ;
    const u16* Bb = Bt + (size_t)z * bZ;
    if (mode == 4) {
        Ab += (size_t)baseE * lda;
        Bb += (size_t)e * ((size_t)DD * FFD);
    }

    const int wave = tid >> 6, lane = tid & 63;
    const int wm = (wave & 1) * 64, wn = (wave >> 1) * 64;
    const int fm = lane & 15;
    const int g  = lane >> 4;

    // staging: wave w covers tile rows [w*32, w*32+32), 2 instrs per operand
    const int lrow = lane >> 2;             // 0..15
    const int lgrp = lane & 3;              // 0..3
    const int cg   = (lgrp ^ ((lrow >> 1) & 3)) * 8;   // swizzled col group
    const int r0   = wave * 32 + lrow;
    const u16 *aG0, *aG1;
    if (mode == 2) {
        const int t0 = rowtok[baseE + m0 + r0];
        const int t1 = rowtok[baseE + m0 + r0 + 16];
        aG0 = Ab + (size_t)t0 * lda + cg;
        aG1 = Ab + (size_t)t1 * lda + cg;
    } else {
        aG0 = Ab + (size_t)(m0 + r0) * lda + cg;
        aG1 = Ab + (size_t)(m0 + r0 + 16) * lda + cg;
    }
    const u16* bG0 = Bb + (size_t)(n0 + r0) * ldb + cg;
    const u16* bG1 = Bb + (size_t)(n0 + r0 + 16) * ldb + cg;
    u16* aL0 = &As[(wave * 32) * 32];
    u16* aL1 = &As[(wave * 32 + 16) * 32];
    u16* bL0 = &Bs[(wave * 32) * 32];
    u16* bL1 = &Bs[(wave * 32 + 16) * 32];

    // fragment LDS addresses (loop-invariant); read swizzle mirrors store
    const int sw8 = ((fm >> 1) & 3) * 8;
    const u16* pa[4]; const u16* pb[4];
    #pragma unroll
    for (int i = 0; i < 4; i++) {
        pa[i] = &As[(wm + i * 16 + fm) * 32 + ((g * 8) ^ sw8)];
        pb[i] = &Bs[(wn + i * 16 + fm) * 32 + ((g * 8) ^ sw8)];
    }

    f32x4 acc[4][4] = {};

    for (int k0 = 0; k0 < K; k0 += 32) {
        ASYNC16(aG0 + k0, aL0);
        ASYNC16(aG1 + k0, aL1);
        ASYNC16(bG0 + k0, bL0);
        ASYNC16(bG1 + k0, bL1);
        __syncthreads();

        bf16x8 af[4], bf[4];
        #pragma unroll
        for (int i = 0; i < 4; i++) af[i] = *reinterpret_cast<const bf16x8*>(pa[i]);
        #pragma unroll
        for (int j = 0; j < 4; j++) bf[j] = *reinterpret_cast<const bf16x8*>(pb[j]);
        #pragma unroll
        for (int i = 0; i < 4; i++)
            #pragma unroll
            for (int j = 0; j < 4; j++)
                acc[i][j] = MFMA16(af[i], bf[j], acc[i][j]);
        __syncthreads();
    }

    // C/D layout: col = lane&15, row = (lane>>4)*4 + reg   [m89-verified]
    const int cn = lane & 15, cr = (lane >> 4) * 4;

    if (mode == 2) {
        // LDS-repacked epilogue: 4 passes x 32 rows, dwordx4 coalesced stores
        u16* Cs = As;
        #pragma unroll
        for (int i = 0; i < 4; i++) {
            if (i) __syncthreads();
            int tokr[4]; float combr[4];
            #pragma unroll
            for (int r = 0; r < 4; r++)
                tokr[r] = rowtok[baseE + m0 + wm + i * 16 + cr + r];
            #pragma unroll
            for (int r = 0; r < 4; r++)
                combr[r] = comb[(size_t)tokr[r] * NE + z];
            #pragma unroll
            for (int j = 0; j < 4; j++) {
                const int n = n0 + wn + j * 16 + cn;
                const float bias = biasF[(size_t)z * biasZ + n];
                #pragma unroll
                for (int r = 0; r < 4; r++) {
                    float y = fmaxf(acc[i][j][r] + bias, 0.f) * combr[r];
                    Cs[((wave & 1) * 16 + cr + r) * 128 + wn + j * 16 + cn] = f2us(y);
                }
            }
            __syncthreads();
            const int lr2 = tid >> 3, c2 = (tid & 7) * 16;
            const int m2 = m0 + (lr2 >> 4) * 64 + i * 16 + (lr2 & 15);
            u16* dst = outH + (size_t)(baseE + m2) * ldc + n0 + c2;
            *reinterpret_cast<uint4*>(dst) =
                *reinterpret_cast<const uint4*>(&Cs[lr2 * 128 + c2]);
            *reinterpret_cast<uint4*>(dst + 8) =
                *reinterpret_cast<const uint4*>(&Cs[lr2 * 128 + c2 + 8]);
        }
        return;
    }

    #pragma unroll
    for (int i = 0; i < 4; i++) {
        #pragma unroll
        for (int j = 0; j < 4; j++) {
            const int n = n0 + wn + j * 16 + cn;
            #pragma unroll
            for (int r = 0; r < 4; r++) {
                const int m = m0 + wm + i * 16 + cr + r;
                float y = acc[i][j][r];
                if (mode == 0) {
                    y += biasF[n];
                    int which = (n >= 1536) ? 2 : (n >= 768 ? 1 : 0);
                    int nn = n - which * 768;
                    int bb = m >> 10, t = m & 1023;
                    int hh = nn >> 6, d = nn & 63;
                    if (which == 0)
                        outH[(((size_t)(bb * HH + hh) * TT + t) << 6) + d] = f2us(y);
                    else if (which == 1)
                        outH2[(((size_t)(bb * HH + hh) * TT + t) << 6) + d] = f2us(y);
                    else
                        outH3[(((size_t)(bb * HH + hh) * HD + d) << 10) + t] = f2us(y);
                } else {  // mode 3 (baseE=0) and mode 4 (compact rows)
                    float* basep = outF + (size_t)z * cZ;
                    basep[(size_t)(baseE + m) * ldc + n] = y;
                }
            }
        }
    }
}

// ---------------------------------------------------------------------------
// MFMA attention. Block = (qt 32 rows, b*12+h). 4 waves.
// Phase 1: S[32][1024] in accumulators (wave w covers cols w*256..+256).
// zscore is scale-invariant: a = gamma/(std_ddof1(S)+EPS_Z/0.125); shift
// cancels in softmax; cm = max(a*S) for stability.
// Phase 2: P bf16 in LDS; O = P*V via MFMA (V pre-transposed [B,H,64,T]).
// ---------------------------------------------------------------------------
#define PSTR 1032  // u16 stride: byte stride 2064 (16B aligned), dw 516 ≡ 4 mod 8 -> conflict-free b128
__global__ __launch_bounds__(256, 2) void attn_mfma_kernel(
    const u16* __restrict__ Qh, const u16* __restrict__ Kh,
    const u16* __restrict__ VT, const float* __restrict__ gamma_p,
    u16* __restrict__ attn_out)
{
    __shared__ __align__(16) u16 P[32 * PSTR];
    __shared__ float wred[4][32][4];
    __shared__ float dred[4][32];
    __shared__ float aArr[32], cmArr[32], dinvArr[32];

    const int qt = blockIdx.x, bh = blockIdx.y;
    const int b = bh / HH, h = bh - b * HH;
    const int tid = threadIdx.x, wave = tid >> 6, lane = tid & 63;
    const int g = lane >> 4, fm = lane & 15;
    const float gamma = gamma_p[0];
    const int m0 = qt * 32;
    const u16* Qp = Qh + (size_t)bh * TT * HD;
    const u16* Kp = Kh + (size_t)bh * TT * HD;
    const u16* Vp = VT + (size_t)bh * HD * TT;

    bf16x8 af[2][2];
    #pragma unroll
    for (int mi = 0; mi < 2; mi++)
        #pragma unroll
        for (int ks = 0; ks < 2; ks++)
            af[mi][ks] = *reinterpret_cast<const bf16x8*>(
                Qp + (size_t)(m0 + mi * 16 + fm) * HD + ks * 32 + g * 8);

    const int n0w = wave * 256;
    f32x4 acc[16][2] = {};
    #pragma unroll
    for (int nj = 0; nj < 16; nj++) {
        const u16* kp = Kp + (size_t)(n0w + nj * 16 + fm) * HD + g * 8;
        bf16x8 b0 = *reinterpret_cast<const bf16x8*>(kp);
        bf16x8 b1 = *reinterpret_cast<const bf16x8*>(kp + 32);
        acc[nj][0] = MFMA16(af[0][0], b0, acc[nj][0]);
        acc[nj][0] = MFMA16(af[0][1], b1, acc[nj][0]);
        acc[nj][1] = MFMA16(af[1][0], b0, acc[nj][1]);
        acc[nj][1] = MFMA16(af[1][1], b1, acc[nj][1]);
    }

    #pragma unroll
    for (int mi = 0; mi < 2; mi++) {
        #pragma unroll
        for (int r = 0; r < 4; r++) {
            float s1 = 0.f, s2 = 0.f, mx = -3.4e38f, mn = 3.4e38f;
            #pragma unroll
            for (int nj = 0; nj < 16; nj++) {
                float v = acc[nj][mi][r];
                s1 += v; s2 = fmaf(v, v, s2);
                mx = fmaxf(mx, v); mn = fminf(mn, v);
            }
            #pragma unroll
            for (int msk = 1; msk < 16; msk <<= 1) {
                s1 += __shfl_xor(s1, msk);
                s2 += __shfl_xor(s2, msk);
                mx = fmaxf(mx, __shfl_xor(mx, msk));
                mn = fminf(mn, __shfl_xor(mn, msk));
            }
            if (fm == 0) {
                int row = mi * 16 + g * 4 + r;
                wred[wave][row][0] = s1; wred[wave][row][1] = s2;
                wred[wave][row][2] = mx; wred[wave][row][3] = mn;
            }
        }
    }
    __syncthreads();
    if (tid < 32) {
        float s1 = 0.f, s2 = 0.f, mx = -3.4e38f, mn = 3.4e38f;
        #pragma unroll
        for (int w = 0; w < 4; w++) {
            s1 += wred[w][tid][0]; s2 += wred[w][tid][1];
            mx = fmaxf(mx, wred[w][tid][2]); mn = fminf(mn, wred[w][tid][3]);
        }
        float var = (s2 - s1 * s1 * (1.f / TT)) * (1.f / (TT - 1));
        var = fmaxf(var, 0.f);
        float a = gamma / (sqrtf(var) + 8e-5f);
        aArr[tid] = a;
        cmArr[tid] = (a >= 0.f) ? a * mx : a * mn;
    }
    __syncthreads();

    #pragma unroll
    for (int mi = 0; mi < 2; mi++) {
        #pragma unroll
        for (int r = 0; r < 4; r++) {
            const int row = mi * 16 + g * 4 + r;
            const float a = aArr[row], cm = cmArr[row];
            float dp = 0.f;
            #pragma unroll
            for (int nj = 0; nj < 16; nj++) {
                float p = __expf(fmaf(a, acc[nj][mi][r], -cm));
                u16 pb = f2us(p);
                dp += us2f(pb);
                P[row * PSTR + n0w + nj * 16 + fm] = pb;
            }
            #pragma unroll
            for (int msk = 1; msk < 16; msk <<= 1) dp += __shfl_xor(dp, msk);
            if (fm == 0) dred[wave][row] = dp;
        }
    }
    __syncthreads();
    if (tid < 32)
        dinvArr[tid] = 1.f / (dred[0][tid] + dred[1][tid] + dred[2][tid] + dred[3][tid]);
    __syncthreads();

    f32x4 oacc[2] = {};
    #pragma unroll 4
    for (int ks = 0; ks < 32; ks++) {
        bf16x8 bv = *reinterpret_cast<const bf16x8*>(
            Vp + (size_t)(wave * 16 + fm) * TT + ks * 32 + g * 8);
        bf16x8 a0 = *reinterpret_cast<const bf16x8*>(&P[(size_t)fm * PSTR + ks * 32 + g * 8]);
        bf16x8 a1 = *reinterpret_cast<const bf16x8*>(&P[(size_t)(16 + fm) * PSTR + ks * 32 + g * 8]);
        oacc[0] = MFMA16(a0, bv, oacc[0]);
        oacc[1] = MFMA16(a1, bv, oacc[1]);
    }
    #pragma unroll
    for (int mi = 0; mi < 2; mi++) {
        #pragma unroll
        for (int r = 0; r < 4; r++) {
            int row = mi * 16 + g * 4 + r;
            int t = m0 + row;
            attn_out[((size_t)(b * TT + t)) * DD + h * HD + wave * 16 + fm] =
                f2us(oacc[mi][r] * dinvArr[row]);
        }
    }
}

// ---------------------------------------------------------------------------
// LN1 fused: r1 = p0+p1+p2+p3 (Wo split-K partials) + src + bo; layernorm ->
// x fp32 + xh bf16.
// ---------------------------------------------------------------------------
__global__ __launch_bounds__(256) void ln1_kernel(
    const float* __restrict__ p0, const float* __restrict__ p1,
    const float* __restrict__ p2, const float* __restrict__ p3,
    const float* __restrict__ src, const float* __restrict__ bo,
    const float* __restrict__ g, const float* __restrict__ bta,
    float* __restrict__ outF, u16* __restrict__ outH)
{
    const int row = blockIdx.x, tid = threadIdx.x;
    __shared__ float red[256];
    const size_t base = (size_t)row * DD;
    float v[3];
    #pragma unroll
    for (int i = 0; i < 3; i++) {
        int c = tid + i * 256;
        v[i] = p0[base + c] + p1[base + c] + p2[base + c] + p3[base + c]
             + src[base + c] + bo[c];
    }
    float s = v[0] + v[1] + v[2];
    red[tid] = s; __syncthreads();
    #pragma unroll
    for (int o = 128; o > 0; o >>= 1) { if (tid < o) red[tid] += red[tid + o]; __syncthreads(); }
    const float mean = red[0] * (1.f / 768.f);
    __syncthreads();
    float qv = 0.f;
    #pragma unroll
    for (int i = 0; i < 3; i++) { float d = v[i] - mean; qv += d * d; }
    red[tid] = qv; __syncthreads();
    #pragma unroll
    for (int o = 128; o > 0; o >>= 1) { if (tid < o) red[tid] += red[tid + o]; __syncthreads(); }
    const float var = red[0] * (1.f / 768.f);
    const float rs = rsqrtf(var + 1e-5f);
    #pragma unroll
    for (int i = 0; i < 3; i++) {
        int c = tid + i * 256;
        float o = (v[i] - mean) * rs * g[c] + bta[c];
        outF[base + c] = o;
        outH[base + c] = f2us(o);
    }
}

// ---------------------------------------------------------------------------
// LN2 (compact): t = x + sum_z sum_{i=0,1} pslab[z][tok2row[t,i]] + comb*b2;
// layernorm -> out. Gathered rows are contiguous (coalesced within a row).
// ---------------------------------------------------------------------------
__global__ __launch_bounds__(256) void ln2_kernel(
    const float* __restrict__ x, const float* __restrict__ pslab,
    const int* __restrict__ tok2row,
    const float* __restrict__ comb, const float* __restrict__ b2,
    const float* __restrict__ g, const float* __restrict__ bta,
    float* __restrict__ outF)
{
    const int row = blockIdx.x, tid = threadIdx.x;
    __shared__ float red[256];
    const size_t base = (size_t)row * DD;
    const int r0 = tok2row[row * 2], r1 = tok2row[row * 2 + 1];
    const float* q0 = pslab + (size_t)r0 * DD;
    const float* q1 = pslab + (size_t)r1 * DD;
    const float c0 = comb[row * NE + 0], c1 = comb[row * NE + 1];
    const float c2 = comb[row * NE + 2], c3 = comb[row * NE + 3];
    float v[3];
    #pragma unroll
    for (int i = 0; i < 3; i++) {
        int c = tid + i * 256;
        float t = x[base + c];
        t += q0[c] + q0[SLABZ + c] + q0[2 * SLABZ + c] + q0[3 * SLABZ + c];
        t += q1[c] + q1[SLABZ + c] + q1[2 * SLABZ + c] + q1[3 * SLABZ + c];
        t = fmaf(c0, b2[c], t);
        t = fmaf(c1, b2[DD + c], t);
        t = fmaf(c2, b2[2 * DD + c], t);
        t = fmaf(c3, b2[3 * DD + c], t);
        v[i] = t;
    }
    float s = v[0] + v[1] + v[2];
    red[tid] = s; __syncthreads();
    #pragma unroll
    for (int o = 128; o > 0; o >>= 1) { if (tid < o) red[tid] += red[tid + o]; __syncthreads(); }
    const float mean = red[0] * (1.f / 768.f);
    __syncthreads();
    float qv = 0.f;
    #pragma unroll
    for (int i = 0; i < 3; i++) { float d = v[i] - mean; qv += d * d; }
    red[tid] = qv; __syncthreads();
    #pragma unroll
    for (int o = 128; o > 0; o >>= 1) { if (tid < o) red[tid] += red[tid + o]; __syncthreads(); }
    const float var = red[0] * (1.f / 768.f);
    const float rs = rsqrtf(var + 1e-5f);
    #pragma unroll
    for (int i = 0; i < 3; i++) {
        int c = tid + i * 256;
        outF[base + c] = (v[i] - mean) * rs * g[c] + bta[c];
    }
}

// ---------------------------------------------------------------------------
// Gate: one wave per token. softmax over E=4, top-2 -> combine weights.
// Also assigns compact slots: slot = atomicAdd(cnt[e]); eslot = (e<<16)|slot.
// ---------------------------------------------------------------------------
__global__ __launch_bounds__(256) void gate_kernel(
    const float* __restrict__ x, const float* __restrict__ Wg,
    const float* __restrict__ bg, float* __restrict__ comb,
    int* __restrict__ cnt, int* __restrict__ eslot)
{
    const int wid = threadIdx.x >> 6, lane = threadIdx.x & 63;
    const int t = blockIdx.x * 4 + wid;
    const float* xr = x + (size_t)t * DD;
    float g[NE];
    #pragma unroll
    for (int e = 0; e < NE; e++) {
        float p = 0.f;
        for (int d = lane; d < DD; d += 64) p += xr[d] * Wg[e * DD + d];
        #pragma unroll
        for (int off = 32; off > 0; off >>= 1) p += __shfl_down(p, off, 64);
        g[e] = p;
    }
    if (lane == 0) {
        float m = -1e30f;
        #pragma unroll
        for (int e = 0; e < NE; e++) { g[e] += bg[e]; m = fmaxf(m, g[e]); }
        float ex[NE], s = 0.f;
        #pragma unroll
        for (int e = 0; e < NE; e++) { ex[e] = __expf(g[e] - m); s += ex[e]; }
        #pragma unroll
        for (int e = 0; e < NE; e++) ex[e] /= s;
        int e1 = 0;
        #pragma unroll
        for (int e = 1; e < NE; e++) if (ex[e] > ex[e1]) e1 = e;
        int e2 = -1;
        #pragma unroll
        for (int e = 0; e < NE; e++) if (e != e1 && (e2 < 0 || ex[e] > ex[e2])) e2 = e;
        float c[NE] = {0.f, 0.f, 0.f, 0.f};
        c[e1] = ex[e1]; c[e2] = ex[e2];
        #pragma unroll
        for (int e = 0; e < NE; e++) comb[(size_t)t * NE + e] = c[e];
        const int s1 = atomicAdd(&cnt[e1], 1);
        const int s2 = atomicAdd(&cnt[e2], 1);
        eslot[t * 2 + 0] = (e1 << 16) | s1;
        eslot[t * 2 + 1] = (e2 << 16) | s2;
    }
}

extern "C" void kernel_launch(void* const* d_in, const int* in_sizes, int n_in,
                              void* d_out, int out_size, void* d_ws, size_t ws_size,
                              hipStream_t stream)
{
    const float* src  = (const float*)d_in[0];
    const float* Wq   = (const float*)d_in[2];  const float* bq = (const float*)d_in[3];
    const float* Wk   = (const float*)d_in[4];  const float* bk = (const float*)d_in[5];
    const float* Wv   = (const float*)d_in[6];  const float* bv = (const float*)d_in[7];
    const float* Wo   = (const float*)d_in[8];  const float* bo = (const float*)d_in[9];
    const float* gam  = (const float*)d_in[10];
    const float* ln1g = (const float*)d_in[11]; const float* ln1b = (const float*)d_in[12];
    const float* ln2g = (const float*)d_in[13]; const float* ln2b = (const float*)d_in[14];
    const float* Wg   = (const float*)d_in[15]; const float* bg = (const float*)d_in[16];
    const float* W1   = (const float*)d_in[17]; const float* b1 = (const float*)d_in[18];
    const float* W2   = (const float*)d_in[19]; const float* b2 = (const float*)d_in[20];
    (void)ws_size; (void)in_sizes; (void)n_in; (void)out_size;

    char* ws = (char*)d_ws;
    // Region B [0, 56,623,104): time-shared.
    //   W1T    at B+0          18,874,368  (written in conversions, read by FF1)
    //   wop    at B+18,874,368 25,165,824  (Wo partials; dead after LN1)
    //   pslab  at B+0          56,623,104  (FF2 partials, 4 slabs x CROWS x 768 f32;
    //                                       written after FF1 -> overlay is safe)
    u16*   W1T  = (u16*)(ws);
    float* wop  = (float*)(ws + 18874368);
    float* pslab= (float*)(ws);
    u16*   W2T  = (u16*)(ws + 56623104);               // 18,874,368 (live through FF2)
    u16*   hb   = (u16*)(ws + 75497472);               // 28,311,552 compact FF1 out [CROWS][3072]
    float* x    = (float*)(ws + 103809024);            //  6,291,456
    u16*   xh   = (u16*)(ws + 110100480);              //  3,145,728
    float* comb = (float*)(ws + 113246208);            //     32,768
    float* bqkv = (float*)(ws + 113278976);            //      9,216
    int*   cnt    = (int*)(ws + 113288192);            //         64
    int*   rowtok = (int*)(ws + 113288256);            //     18,432 (CROWS)
    int*   eslot  = (int*)(ws + 113306688);            //     16,384
    int*   tok2row= (int*)(ws + 113323072);            //     16,384  -> total 113,339,456
    // attn-phase aliases inside hb region (all dead before FF1 writes hb)
    char* H = ws + 75497472;
    u16*   Qh     = (u16*)(H);                         //  3,145,728
    u16*   Kh     = (u16*)(H + 3145728);               //  3,145,728
    u16*   VTh    = (u16*)(H + 6291456);               //  3,145,728
    u16*   src_h  = (u16*)(H + 9437184);               //  3,145,728
    u16*   attn_h = (u16*)(H + 12582912);              //  3,145,728
    u16*   WqkvH  = (u16*)(H + 15728640);              //  3,538,944
    u16*   WoH    = (u16*)(H + 19267584);              //  1,179,648 (ends 20,447,232 < 28,311,552)
    const long PZ = (long)NTOK * DD;

    const int DW = DD * DD;  // 589824

    // ---- weight/activation conversions ----
    convert_kernel<<<(NTOK * DD / 8 + 255) / 256, 256, 0, stream>>>(src, src_h, NTOK * DD / 8);
    convert_kernel<<<(DW / 8 + 255) / 256, 256, 0, stream>>>(Wq, WqkvH, DW / 8);
    convert_kernel<<<(DW / 8 + 255) / 256, 256, 0, stream>>>(Wk, WqkvH + DW, DW / 8);
    convert_kernel<<<(DW / 8 + 255) / 256, 256, 0, stream>>>(Wv, WqkvH + 2 * DW, DW / 8);
    convert_kernel<<<(DW / 8 + 255) / 256, 256, 0, stream>>>(Wo, WoH, DW / 8);
    hipMemcpyAsync(bqkv, bq, DD * 4, hipMemcpyDeviceToDevice, stream);
    hipMemcpyAsync(bqkv + DD, bk, DD * 4, hipMemcpyDeviceToDevice, stream);
    hipMemcpyAsync(bqkv + 2 * DD, bv, DD * 4, hipMemcpyDeviceToDevice, stream);
    // W1[e]: [768,3072] -> [3072,768] per expert
    transpose_convert_kernel<<<dim3(FFD / 32, DD / 32, NE), 256, 0, stream>>>(
        W1, W1T, FFD, DD, (long)DD * FFD, (long)FFD * DD);
    // W2[e]: [3072,768] -> per-expert slab W2T[e][n][k], n-stride 3072
    transpose_convert_kernel<<<dim3(DD / 32, FFD / 32, NE), 256, 0, stream>>>(
        W2, W2T, DD, FFD, (long)FFD * DD, (long)FFD * DD);
    zero_kernel<<<1, 256, 0, stream>>>(cnt, rowtok);

    // ---- QKV (batched, N=2304) -> bf16 Q,K [B,H,T,64], V^T [B,H,64,T] ----
    gemm_bt_kernel<<<dim3(2304 / 128, NTOK / 128, 1), 256, 0, stream>>>(
        src_h, DD, 0, WqkvH, DD, 0, DD, 0, 0,
        nullptr, Qh, Kh, VTh, 0, 0, bqkv, 0, nullptr, nullptr, nullptr);

    // ---- attention (MFMA) ----
    attn_mfma_kernel<<<dim3(TT / 32, BB * HH), 256, 0, stream>>>(
        Qh, Kh, VTh, gam, attn_h);

    // ---- Wo projection split-K x4 -> fp32 partials in wop ----
    gemm_bt_kernel<<<dim3(DD / 128, NTOK / 128, 4), 256, 0, stream>>>(
        attn_h, DD, 192L, WoH, DD, 192L, 192, 3, 0,
        wop, nullptr, nullptr, nullptr, DD, PZ, nullptr, 0, nullptr, nullptr, nullptr);

    // ---- LN1 (sums Wo partials + residual + bias inline) ----
    ln1_kernel<<<NTOK, 256, 0, stream>>>(
        wop, wop + PZ, wop + 2 * PZ, wop + 3 * PZ, src, bo,
        ln1g, ln1b, x, xh);

    // ---- gate (+ compact slot assignment) ----
    gate_kernel<<<NTOK / 4, 256, 0, stream>>>(x, Wg, bg, comb, cnt, eslot);
    build_kernel<<<NTOK / 256, 256, 0, stream>>>(cnt, eslot, rowtok, tok2row);

    // ---- FF1 compact (top-2 only): gathered A-rows; ~47% fewer live tiles.
    //      Inactive (mt*128 >= cnt[e]) blocks exit immediately. ----
    gemm_bt_kernel<<<dim3(1536, 1, 1), 256, 0, stream>>>(
        xh, DD, 0, W1T, DD, (long)FFD * DD, DD, 2, 1,
        nullptr, hb, nullptr, nullptr, FFD, 0, b1, FFD, rowtok, cnt, comb);

    // ---- FF2 compact: per-expert K=3072 split-K x4 (aZ=bZ=768 k-slice),
    //      partials at compact rows -> 4 slabs; each XCD owns two (e,z)
    //      B-slices (L2-resident) ----
    gemm_bt_kernel<<<dim3(1536, 1, 1), 256, 0, stream>>>(
        hb, FFD, 768L, W2T, FFD, 768L, 768, 4, 3,
        pslab, nullptr, nullptr, nullptr, DD, SLABZ, nullptr, 0, rowtok, cnt, nullptr);

    // ---- LN2 (x + gathered compact partials + comb*b2, then layernorm) ----
    ln2_kernel<<<NTOK, 256, 0, stream>>>(
        x, pslab, tok2row, comb, b2, ln2g, ln2b, (float*)d_out);
}

// Round 2
// 398.208 us; speedup vs baseline: 1.1722x; 1.1464x over previous
//
#include <hip/hip_runtime.h>

typedef unsigned short u16;
typedef short bf16x8 __attribute__((ext_vector_type(8)));
typedef float f32x4 __attribute__((ext_vector_type(4)));

#define BB 2
#define TT 1024
#define DD 768
#define HH 12
#define HD 64
#define FFD 3072
#define NE 4
#define NTOK (BB*TT)
// compact MoE row space: sum_e ceil(cnt[e]/128)*128 <= 4096 + 4*127 = 4604
#define CROWS 4608
#define SLABZ 3538944L   // CROWS*DD elements per FF2 partial slab

#define MFMA16(a, b, c) __builtin_amdgcn_mfma_f32_16x16x32_bf16((a), (b), (c), 0, 0, 0)

#define ASYNC16(gsrc, ldst)                                                    \
    __builtin_amdgcn_global_load_lds(                                          \
        (const __attribute__((address_space(1))) void*)(gsrc),                 \
        (__attribute__((address_space(3))) void*)(ldst), 16, 0, 0)

__device__ __forceinline__ float us2f(u16 u) {
    return __uint_as_float(((unsigned int)u) << 16);
}
__device__ __forceinline__ u16 f2us(float f) {
    unsigned int x = __float_as_uint(f);
    x += 0x7fffu + ((x >> 16) & 1u);
    return (u16)(x >> 16);
}

// ---------------------------------------------------------------------------
// Flat fp32 -> bf16 convert. n8 = n/8 work items.
// ---------------------------------------------------------------------------
__global__ __launch_bounds__(256) void convert_kernel(
    const float* __restrict__ in, u16* __restrict__ out, int n8)
{
    int i = blockIdx.x * 256 + threadIdx.x;
    if (i >= n8) return;
    const float4* p = reinterpret_cast<const float4*>(in) + (size_t)i * 2;
    float4 a = p[0], b = p[1];
    u16 o[8] = {f2us(a.x), f2us(a.y), f2us(a.z), f2us(a.w),
                f2us(b.x), f2us(b.y), f2us(b.z), f2us(b.w)};
    *reinterpret_cast<uint4*>(out + (size_t)i * 8) = *reinterpret_cast<uint4*>(o);
}

// ---------------------------------------------------------------------------
// Transpose + convert (vectorized): per z, src [.,C] fp32 -> dst bf16 with
// dst[c*dstStride + r]. float4 reads, uint2 (4xbf16) packed writes.
// ---------------------------------------------------------------------------
__global__ __launch_bounds__(256) void transpose_convert_kernel(
    const float* __restrict__ src, u16* __restrict__ dst,
    int C, int dstStride, long srcZ, long dstZ)
{
    __shared__ float tile[32][33];
    const float* s = src + (size_t)blockIdx.z * srcZ;
    u16* d = dst + (size_t)blockIdx.z * dstZ;
    const int c0 = blockIdx.x * 32, r0 = blockIdx.y * 32;
    const int tid = threadIdx.x;
    {
        const int r = tid >> 3, cs = (tid & 7) * 4;
        float4 v = *reinterpret_cast<const float4*>(&s[(size_t)(r0 + r) * C + c0 + cs]);
        tile[r][cs] = v.x; tile[r][cs + 1] = v.y;
        tile[r][cs + 2] = v.z; tile[r][cs + 3] = v.w;
    }
    __syncthreads();
    {
        const int c = tid >> 3, rs = (tid & 7) * 4;
        u16 o[4] = {f2us(tile[rs][c]), f2us(tile[rs + 1][c]),
                    f2us(tile[rs + 2][c]), f2us(tile[rs + 3][c])};
        *reinterpret_cast<uint2*>(&d[(size_t)(c0 + c) * dstStride + r0 + rs]) =
            *reinterpret_cast<uint2*>(o);
    }
}

// ---------------------------------------------------------------------------
// Deterministic compact-slot assignment (replaces atomics): single block,
// Hillis-Steele prefix scan of per-thread expert counts over 2048 tokens
// (8 tokens/thread, 2 entries each). Also zeroes rowtok padding (padding
// rows keep token 0: valid reads, outputs never consumed) and writes cnt.
// ---------------------------------------------------------------------------
__global__ __launch_bounds__(256) void scan_build_kernel(
    const int* __restrict__ epack, int* __restrict__ cnt,
    int* __restrict__ rowtok, int* __restrict__ tok2row)
{
    __shared__ int sc[256][4];
    const int tid = threadIdx.x;
    for (int i = tid; i < CROWS; i += 256) rowtok[i] = 0;
    int ep[8];
    int l0 = 0, l1 = 0, l2 = 0, l3 = 0;
    #pragma unroll
    for (int i = 0; i < 8; i++) {
        const int v = epack[tid * 8 + i];
        ep[i] = v;
        const int a = v & 15, b = (v >> 4) & 15;
        l0 += (a == 0) + (b == 0);
        l1 += (a == 1) + (b == 1);
        l2 += (a == 2) + (b == 2);
        l3 += (a == 3) + (b == 3);
    }
    sc[tid][0] = l0; sc[tid][1] = l1; sc[tid][2] = l2; sc[tid][3] = l3;
    __syncthreads();
    for (int off = 1; off < 256; off <<= 1) {
        int v0 = 0, v1 = 0, v2 = 0, v3 = 0;
        if (tid >= off) {
            v0 = sc[tid - off][0]; v1 = sc[tid - off][1];
            v2 = sc[tid - off][2]; v3 = sc[tid - off][3];
        }
        __syncthreads();
        if (tid >= off) {
            sc[tid][0] += v0; sc[tid][1] += v1;
            sc[tid][2] += v2; sc[tid][3] += v3;
        }
        __syncthreads();
    }
    const int t0 = sc[255][0], t1 = sc[255][1], t2 = sc[255][2], t3 = sc[255][3];
    if (tid == 0) { cnt[0] = t0; cnt[1] = t1; cnt[2] = t2; cnt[3] = t3; }
    const int b1 = (t0 + 127) & ~127;
    const int b2 = b1 + ((t1 + 127) & ~127);
    const int b3 = b2 + ((t2 + 127) & ~127);
    int r0 = sc[tid][0] - l0;
    int r1 = b1 + sc[tid][1] - l1;
    int r2 = b2 + sc[tid][2] - l2;
    int r3 = b3 + sc[tid][3] - l3;
    #pragma unroll
    for (int i = 0; i < 8; i++) {
        const int t = tid * 8 + i;
        const int a = ep[i] & 15, b = (ep[i] >> 4) & 15;
        const int ra = (a == 0) ? r0++ : (a == 1) ? r1++ : (a == 2) ? r2++ : r3++;
        rowtok[ra] = t; tok2row[t * 2] = ra;
        const int rb = (b == 0) ? r0++ : (b == 1) ? r1++ : (b == 2) ? r2++ : r3++;
        rowtok[rb] = t; tok2row[t * 2 + 1] = rb;
    }
}

// ---------------------------------------------------------------------------
// bf16 MFMA GEMM: C[M,N] = A[M,K] * Bt[N,K]^T  (both row-major, K-contiguous)
// 128x128 tile, 4 waves, 16x16x32 MFMA, fp32 accum.
// Staging: global_load_lds 16B into unpadded [128][32] u16 LDS; XOR column-
// group swizzle at the global-source side (bank-balanced, conflict-free).
// modes:
//  0 QKV:  y=acc+biasF[n]; bf16 scatter: Q,K -> [B,H,T,64]; V -> VT [B,H,64,T]
//  2 FF1 (COMPACT): A-rows gathered via rowtok[baseE + tilerow]; active iff
//          by*128 < cnt[e]; y=relu(acc+b1[e,n])*comb[tok,e] -> hb[crow][FFD]
//          via LDS-repacked dwordx4 stores
//  3 Wo split-K partial: outF + z*cZ, plain fp32 store
//  4 FF2 (COMPACT): A=hb compact rows (baseE folded into Ab), B=W2T expert
//          slab + k-slice z; partial fp32 -> pslab + z*cZ at compact rows
// swz (XCD-aware flat-grid decode; fid%8 assumed = XCD):
//  0: 3D grid as-is
//  1: FF1 flat 1536: xcd=fid&7; r=fid>>3; ne=xcd*12+(r%12); by=r/12 (mt);
//     bx=ne%24 (n); e=ne/24   -> each XCD owns 12 (n,e) B-tiles (L2-resident)
//  3: FF2 flat 1536: xcd=fid&7; r=fid>>3; half=r>=96; ez=xcd*2+half;
//     e=ez>>2; z=ez&3; rr=r-96*half; bx=rr%6; by=rr/6
//     -> each XCD owns two (e,z) B-slices (1.18MB each, L2-resident)
// ---------------------------------------------------------------------------
__global__ __launch_bounds__(256) void gemm_bt_kernel(
    const u16* __restrict__ A, int lda, long aZ,
    const u16* __restrict__ Bt, int ldb, long bZ,
    int K, int mode, int swz,
    float* __restrict__ outF, u16* __restrict__ outH,
    u16* __restrict__ outH2, u16* __restrict__ outH3,
    int ldc, long cZ,
    const float* __restrict__ biasF, int biasZ,
    const int* __restrict__ rowtok, const int* __restrict__ cntp,
    const float* __restrict__ comb)
{
    __shared__ __align__(16) u16 As[128 * 32];
    __shared__ __align__(16) u16 Bs[128 * 32];
    const int tid = threadIdx.x;
    int bx, by, z, e = 0, baseE = 0;
    if (swz == 3) {
        const int fid = blockIdx.x;
        const int xcd = fid & 7; int r = fid >> 3;
        const int half = (r >= 96) ? 1 : 0; r -= half * 96;
        bx = r % 6; by = r / 6;
        const int ez = xcd * 2 + half; e = ez >> 2; z = ez & 3;
    } else if (swz == 1) {
        const int fid = blockIdx.x;
        const int xcd = fid & 7; const int r = fid >> 3;
        const int ne = xcd * 12 + (r % 12);
        by = r / 12; bx = ne % 24; e = ne / 24; z = e;
    } else {
        bx = blockIdx.x; by = blockIdx.y; z = blockIdx.z;
    }
    if (mode == 2 || mode == 4) {
        const int q0 = (cntp[0] + 127) & ~127;
        const int q1 = (cntp[1] + 127) & ~127;
        const int q2 = (cntp[2] + 127) & ~127;
        baseE = (e > 0 ? q0 : 0) + (e > 1 ? q1 : 0) + (e > 2 ? q2 : 0);
        if (by * 128 >= cntp[e]) return;   // uniform per block: safe early-exit
    }
    const int m0 = by * 128, n0 = bx * 128;
    const u16* Ab = A + (size_t)z * aZ;
    const u16* Bb = Bt + (size_t)z * bZ;
    if (mode == 4) {
        Ab += (size_t)baseE * lda;
        Bb += (size_t)e * ((size_t)DD * FFD);
    }

    const int wave = tid >> 6, lane = tid & 63;
    const int wm = (wave & 1) * 64, wn = (wave >> 1) * 64;
    const int fm = lane & 15;
    const int g  = lane >> 4;

    // staging: wave w covers tile rows [w*32, w*32+32), 2 instrs per operand
    const int lrow = lane >> 2;             // 0..15
    const int lgrp = lane & 3;              // 0..3
    const int cg   = (lgrp ^ ((lrow >> 1) & 3)) * 8;   // swizzled col group
    const int r0   = wave * 32 + lrow;
    const u16 *aG0, *aG1;
    if (mode == 2) {
        const int t0 = rowtok[baseE + m0 + r0];
        const int t1 = rowtok[baseE + m0 + r0 + 16];
        aG0 = Ab + (size_t)t0 * lda + cg;
        aG1 = Ab + (size_t)t1 * lda + cg;
    } else {
        aG0 = Ab + (size_t)(m0 + r0) * lda + cg;
        aG1 = Ab + (size_t)(m0 + r0 + 16) * lda + cg;
    }
    const u16* bG0 = Bb + (size_t)(n0 + r0) * ldb + cg;
    const u16* bG1 = Bb + (size_t)(n0 + r0 + 16) * ldb + cg;
    u16* aL0 = &As[(wave * 32) * 32];
    u16* aL1 = &As[(wave * 32 + 16) * 32];
    u16* bL0 = &Bs[(wave * 32) * 32];
    u16* bL1 = &Bs[(wave * 32 + 16) * 32];

    // fragment LDS addresses (loop-invariant); read swizzle mirrors store
    const int sw8 = ((fm >> 1) & 3) * 8;
    const u16* pa[4]; const u16* pb[4];
    #pragma unroll
    for (int i = 0; i < 4; i++) {
        pa[i] = &As[(wm + i * 16 + fm) * 32 + ((g * 8) ^ sw8)];
        pb[i] = &Bs[(wn + i * 16 + fm) * 32 + ((g * 8) ^ sw8)];
    }

    f32x4 acc[4][4] = {};

    for (int k0 = 0; k0 < K; k0 += 32) {
        ASYNC16(aG0 + k0, aL0);
        ASYNC16(aG1 + k0, aL1);
        ASYNC16(bG0 + k0, bL0);
        ASYNC16(bG1 + k0, bL1);
        __syncthreads();

        bf16x8 af[4], bf[4];
        #pragma unroll
        for (int i = 0; i < 4; i++) af[i] = *reinterpret_cast<const bf16x8*>(pa[i]);
        #pragma unroll
        for (int j = 0; j < 4; j++) bf[j] = *reinterpret_cast<const bf16x8*>(pb[j]);
        #pragma unroll
        for (int i = 0; i < 4; i++)
            #pragma unroll
            for (int j = 0; j < 4; j++)
                acc[i][j] = MFMA16(af[i], bf[j], acc[i][j]);
        __syncthreads();
    }

    // C/D layout: col = lane&15, row = (lane>>4)*4 + reg   [m89-verified]
    const int cn = lane & 15, cr = (lane >> 4) * 4;

    if (mode == 2) {
        // LDS-repacked epilogue: 4 passes x 32 rows, dwordx4 coalesced stores
        u16* Cs = As;
        #pragma unroll
        for (int i = 0; i < 4; i++) {
            if (i) __syncthreads();
            int tokr[4]; float combr[4];
            #pragma unroll
            for (int r = 0; r < 4; r++)
                tokr[r] = rowtok[baseE + m0 + wm + i * 16 + cr + r];
            #pragma unroll
            for (int r = 0; r < 4; r++)
                combr[r] = comb[(size_t)tokr[r] * NE + z];
            #pragma unroll
            for (int j = 0; j < 4; j++) {
                const int n = n0 + wn + j * 16 + cn;
                const float bias = biasF[(size_t)z * biasZ + n];
                #pragma unroll
                for (int r = 0; r < 4; r++) {
                    float y = fmaxf(acc[i][j][r] + bias, 0.f) * combr[r];
                    Cs[((wave & 1) * 16 + cr + r) * 128 + wn + j * 16 + cn] = f2us(y);
                }
            }
            __syncthreads();
            const int lr2 = tid >> 3, c2 = (tid & 7) * 16;
            const int m2 = m0 + (lr2 >> 4) * 64 + i * 16 + (lr2 & 15);
            u16* dst = outH + (size_t)(baseE + m2) * ldc + n0 + c2;
            *reinterpret_cast<uint4*>(dst) =
                *reinterpret_cast<const uint4*>(&Cs[lr2 * 128 + c2]);
            *reinterpret_cast<uint4*>(dst + 8) =
                *reinterpret_cast<const uint4*>(&Cs[lr2 * 128 + c2 + 8]);
        }
        return;
    }

    #pragma unroll
    for (int i = 0; i < 4; i++) {
        #pragma unroll
        for (int j = 0; j < 4; j++) {
            const int n = n0 + wn + j * 16 + cn;
            #pragma unroll
            for (int r = 0; r < 4; r++) {
                const int m = m0 + wm + i * 16 + cr + r;
                float y = acc[i][j][r];
                if (mode == 0) {
                    y += biasF[n];
                    int which = (n >= 1536) ? 2 : (n >= 768 ? 1 : 0);
                    int nn = n - which * 768;
                    int bb = m >> 10, t = m & 1023;
                    int hh = nn >> 6, d = nn & 63;
                    if (which == 0)
                        outH[(((size_t)(bb * HH + hh) * TT + t) << 6) + d] = f2us(y);
                    else if (which == 1)
                        outH2[(((size_t)(bb * HH + hh) * TT + t) << 6) + d] = f2us(y);
                    else
                        outH3[(((size_t)(bb * HH + hh) * HD + d) << 10) + t] = f2us(y);
                } else {  // mode 3 (baseE=0) and mode 4 (compact rows)
                    float* basep = outF + (size_t)z * cZ;
                    basep[(size_t)(baseE + m) * ldc + n] = y;
                }
            }
        }
    }
}

// ---------------------------------------------------------------------------
// MFMA attention. Block = (qt 32 rows, b*12+h). 4 waves.
// Phase 1: S[32][1024] in accumulators (wave w covers cols w*256..+256).
// zscore is scale-invariant: a = gamma/(std_ddof1(S)+EPS_Z/0.125); shift
// cancels in softmax; cm = max(a*S) for stability.
// Phase 2: P bf16 in LDS; O = P*V via MFMA (V pre-transposed [B,H,64,T]).
// ---------------------------------------------------------------------------
#define PSTR 1032  // u16 stride: byte stride 2064 (16B aligned), dw 516 ≡ 4 mod 8 -> conflict-free b128
__global__ __launch_bounds__(256, 2) void attn_mfma_kernel(
    const u16* __restrict__ Qh, const u16* __restrict__ Kh,
    const u16* __restrict__ VT, const float* __restrict__ gamma_p,
    u16* __restrict__ attn_out)
{
    __shared__ __align__(16) u16 P[32 * PSTR];
    __shared__ float wred[4][32][4];
    __shared__ float dred[4][32];
    __shared__ float aArr[32], cmArr[32], dinvArr[32];

    const int qt = blockIdx.x, bh = blockIdx.y;
    const int b = bh / HH, h = bh - b * HH;
    const int tid = threadIdx.x, wave = tid >> 6, lane = tid & 63;
    const int g = lane >> 4, fm = lane & 15;
    const float gamma = gamma_p[0];
    const int m0 = qt * 32;
    const u16* Qp = Qh + (size_t)bh * TT * HD;
    const u16* Kp = Kh + (size_t)bh * TT * HD;
    const u16* Vp = VT + (size_t)bh * HD * TT;

    bf16x8 af[2][2];
    #pragma unroll
    for (int mi = 0; mi < 2; mi++)
        #pragma unroll
        for (int ks = 0; ks < 2; ks++)
            af[mi][ks] = *reinterpret_cast<const bf16x8*>(
                Qp + (size_t)(m0 + mi * 16 + fm) * HD + ks * 32 + g * 8);

    const int n0w = wave * 256;
    f32x4 acc[16][2] = {};
    #pragma unroll
    for (int nj = 0; nj < 16; nj++) {
        const u16* kp = Kp + (size_t)(n0w + nj * 16 + fm) * HD + g * 8;
        bf16x8 b0 = *reinterpret_cast<const bf16x8*>(kp);
        bf16x8 b1 = *reinterpret_cast<const bf16x8*>(kp + 32);
        acc[nj][0] = MFMA16(af[0][0], b0, acc[nj][0]);
        acc[nj][0] = MFMA16(af[0][1], b1, acc[nj][0]);
        acc[nj][1] = MFMA16(af[1][0], b0, acc[nj][1]);
        acc[nj][1] = MFMA16(af[1][1], b1, acc[nj][1]);
    }

    #pragma unroll
    for (int mi = 0; mi < 2; mi++) {
        #pragma unroll
        for (int r = 0; r < 4; r++) {
            float s1 = 0.f, s2 = 0.f, mx = -3.4e38f, mn = 3.4e38f;
            #pragma unroll
            for (int nj = 0; nj < 16; nj++) {
                float v = acc[nj][mi][r];
                s1 += v; s2 = fmaf(v, v, s2);
                mx = fmaxf(mx, v); mn = fminf(mn, v);
            }
            #pragma unroll
            for (int msk = 1; msk < 16; msk <<= 1) {
                s1 += __shfl_xor(s1, msk);
                s2 += __shfl_xor(s2, msk);
                mx = fmaxf(mx, __shfl_xor(mx, msk));
                mn = fminf(mn, __shfl_xor(mn, msk));
            }
            if (fm == 0) {
                int row = mi * 16 + g * 4 + r;
                wred[wave][row][0] = s1; wred[wave][row][1] = s2;
                wred[wave][row][2] = mx; wred[wave][row][3] = mn;
            }
        }
    }
    __syncthreads();
    if (tid < 32) {
        float s1 = 0.f, s2 = 0.f, mx = -3.4e38f, mn = 3.4e38f;
        #pragma unroll
        for (int w = 0; w < 4; w++) {
            s1 += wred[w][tid][0]; s2 += wred[w][tid][1];
            mx = fmaxf(mx, wred[w][tid][2]); mn = fminf(mn, wred[w][tid][3]);
        }
        float var = (s2 - s1 * s1 * (1.f / TT)) * (1.f / (TT - 1));
        var = fmaxf(var, 0.f);
        float a = gamma / (sqrtf(var) + 8e-5f);
        aArr[tid] = a;
        cmArr[tid] = (a >= 0.f) ? a * mx : a * mn;
    }
    __syncthreads();

    #pragma unroll
    for (int mi = 0; mi < 2; mi++) {
        #pragma unroll
        for (int r = 0; r < 4; r++) {
            const int row = mi * 16 + g * 4 + r;
            const float a = aArr[row], cm = cmArr[row];
            float dp = 0.f;
            #pragma unroll
            for (int nj = 0; nj < 16; nj++) {
                float p = __expf(fmaf(a, acc[nj][mi][r], -cm));
                u16 pb = f2us(p);
                dp += us2f(pb);
                P[row * PSTR + n0w + nj * 16 + fm] = pb;
            }
            #pragma unroll
            for (int msk = 1; msk < 16; msk <<= 1) dp += __shfl_xor(dp, msk);
            if (fm == 0) dred[wave][row] = dp;
        }
    }
    __syncthreads();
    if (tid < 32)
        dinvArr[tid] = 1.f / (dred[0][tid] + dred[1][tid] + dred[2][tid] + dred[3][tid]);
    __syncthreads();

    f32x4 oacc[2] = {};
    #pragma unroll 4
    for (int ks = 0; ks < 32; ks++) {
        bf16x8 bv = *reinterpret_cast<const bf16x8*>(
            Vp + (size_t)(wave * 16 + fm) * TT + ks * 32 + g * 8);
        bf16x8 a0 = *reinterpret_cast<const bf16x8*>(&P[(size_t)fm * PSTR + ks * 32 + g * 8]);
        bf16x8 a1 = *reinterpret_cast<const bf16x8*>(&P[(size_t)(16 + fm) * PSTR + ks * 32 + g * 8]);
        oacc[0] = MFMA16(a0, bv, oacc[0]);
        oacc[1] = MFMA16(a1, bv, oacc[1]);
    }
    #pragma unroll
    for (int mi = 0; mi < 2; mi++) {
        #pragma unroll
        for (int r = 0; r < 4; r++) {
            int row = mi * 16 + g * 4 + r;
            int t = m0 + row;
            attn_out[((size_t)(b * TT + t)) * DD + h * HD + wave * 16 + fm] =
                f2us(oacc[mi][r] * dinvArr[row]);
        }
    }
}

// ---------------------------------------------------------------------------
// LN1 fused + gate: r1 = p0+p1+p2+p3 (Wo split-K partials) + src + bo;
// layernorm -> x fp32 + xh bf16. Gate fused on the post-LN values held in
// registers: g[e] = sum_c x[c]*Wg[e,c]; thread-0 softmax/top-2 -> comb,
// epack[t] = e1 | (e2<<4). No atomics (slot assignment in scan_build).
// ---------------------------------------------------------------------------
__global__ __launch_bounds__(256) void ln1_kernel(
    const float* __restrict__ p0, const float* __restrict__ p1,
    const float* __restrict__ p2, const float* __restrict__ p3,
    const float* __restrict__ src, const float* __restrict__ bo,
    const float* __restrict__ g, const float* __restrict__ bta,
    const float* __restrict__ Wg, const float* __restrict__ bg,
    float* __restrict__ outF, u16* __restrict__ outH,
    float* __restrict__ comb, int* __restrict__ epack)
{
    const int row = blockIdx.x, tid = threadIdx.x;
    __shared__ float red[256];
    __shared__ float gred[4][4];
    const size_t base = (size_t)row * DD;
    float v[3];
    #pragma unroll
    for (int i = 0; i < 3; i++) {
        int c = tid + i * 256;
        v[i] = p0[base + c] + p1[base + c] + p2[base + c] + p3[base + c]
             + src[base + c] + bo[c];
    }
    float s = v[0] + v[1] + v[2];
    red[tid] = s; __syncthreads();
    #pragma unroll
    for (int o = 128; o > 0; o >>= 1) { if (tid < o) red[tid] += red[tid + o]; __syncthreads(); }
    const float mean = red[0] * (1.f / 768.f);
    __syncthreads();
    float qv = 0.f;
    #pragma unroll
    for (int i = 0; i < 3; i++) { float d = v[i] - mean; qv += d * d; }
    red[tid] = qv; __syncthreads();
    #pragma unroll
    for (int o = 128; o > 0; o >>= 1) { if (tid < o) red[tid] += red[tid + o]; __syncthreads(); }
    const float var = red[0] * (1.f / 768.f);
    const float rs = rsqrtf(var + 1e-5f);
    float ga0 = 0.f, ga1 = 0.f, ga2 = 0.f, ga3 = 0.f;
    #pragma unroll
    for (int i = 0; i < 3; i++) {
        int c = tid + i * 256;
        float o = (v[i] - mean) * rs * g[c] + bta[c];
        outF[base + c] = o;
        outH[base + c] = f2us(o);
        ga0 = fmaf(o, Wg[c], ga0);
        ga1 = fmaf(o, Wg[DD + c], ga1);
        ga2 = fmaf(o, Wg[2 * DD + c], ga2);
        ga3 = fmaf(o, Wg[3 * DD + c], ga3);
    }
    #pragma unroll
    for (int off = 32; off > 0; off >>= 1) {
        ga0 += __shfl_down(ga0, off, 64);
        ga1 += __shfl_down(ga1, off, 64);
        ga2 += __shfl_down(ga2, off, 64);
        ga3 += __shfl_down(ga3, off, 64);
    }
    const int wave = tid >> 6, lane = tid & 63;
    if (lane == 0) {
        gred[wave][0] = ga0; gred[wave][1] = ga1;
        gred[wave][2] = ga2; gred[wave][3] = ga3;
    }
    __syncthreads();
    if (tid == 0) {
        float gg[NE];
        #pragma unroll
        for (int e = 0; e < NE; e++)
            gg[e] = gred[0][e] + gred[1][e] + gred[2][e] + gred[3][e] + bg[e];
        float m = -1e30f;
        #pragma unroll
        for (int e = 0; e < NE; e++) m = fmaxf(m, gg[e]);
        float ex[NE], ssum = 0.f;
        #pragma unroll
        for (int e = 0; e < NE; e++) { ex[e] = __expf(gg[e] - m); ssum += ex[e]; }
        #pragma unroll
        for (int e = 0; e < NE; e++) ex[e] /= ssum;
        int e1 = 0;
        #pragma unroll
        for (int e = 1; e < NE; e++) if (ex[e] > ex[e1]) e1 = e;
        int e2 = -1;
        #pragma unroll
        for (int e = 0; e < NE; e++) if (e != e1 && (e2 < 0 || ex[e] > ex[e2])) e2 = e;
        float c[NE] = {0.f, 0.f, 0.f, 0.f};
        c[e1] = ex[e1]; c[e2] = ex[e2];
        #pragma unroll
        for (int e = 0; e < NE; e++) comb[(size_t)row * NE + e] = c[e];
        epack[row] = e1 | (e2 << 4);
    }
}

// ---------------------------------------------------------------------------
// LN2 (compact): t = x + sum_z sum_{i=0,1} pslab[z][tok2row[t,i]] + comb*b2;
// layernorm -> out. Gathered rows are contiguous (coalesced within a row).
// ---------------------------------------------------------------------------
__global__ __launch_bounds__(256) void ln2_kernel(
    const float* __restrict__ x, const float* __restrict__ pslab,
    const int* __restrict__ tok2row,
    const float* __restrict__ comb, const float* __restrict__ b2,
    const float* __restrict__ g, const float* __restrict__ bta,
    float* __restrict__ outF)
{
    const int row = blockIdx.x, tid = threadIdx.x;
    __shared__ float red[256];
    const size_t base = (size_t)row * DD;
    const int r0 = tok2row[row * 2], r1 = tok2row[row * 2 + 1];
    const float* q0 = pslab + (size_t)r0 * DD;
    const float* q1 = pslab + (size_t)r1 * DD;
    const float c0 = comb[row * NE + 0], c1 = comb[row * NE + 1];
    const float c2 = comb[row * NE + 2], c3 = comb[row * NE + 3];
    float v[3];
    #pragma unroll
    for (int i = 0; i < 3; i++) {
        int c = tid + i * 256;
        float t = x[base + c];
        t += q0[c] + q0[SLABZ + c] + q0[2 * SLABZ + c] + q0[3 * SLABZ + c];
        t += q1[c] + q1[SLABZ + c] + q1[2 * SLABZ + c] + q1[3 * SLABZ + c];
        t = fmaf(c0, b2[c], t);
        t = fmaf(c1, b2[DD + c], t);
        t = fmaf(c2, b2[2 * DD + c], t);
        t = fmaf(c3, b2[3 * DD + c], t);
        v[i] = t;
    }
    float s = v[0] + v[1] + v[2];
    red[tid] = s; __syncthreads();
    #pragma unroll
    for (int o = 128; o > 0; o >>= 1) { if (tid < o) red[tid] += red[tid + o]; __syncthreads(); }
    const float mean = red[0] * (1.f / 768.f);
    __syncthreads();
    float qv = 0.f;
    #pragma unroll
    for (int i = 0; i < 3; i++) { float d = v[i] - mean; qv += d * d; }
    red[tid] = qv; __syncthreads();
    #pragma unroll
    for (int o = 128; o > 0; o >>= 1) { if (tid < o) red[tid] += red[tid + o]; __syncthreads(); }
    const float var = red[0] * (1.f / 768.f);
    const float rs = rsqrtf(var + 1e-5f);
    #pragma unroll
    for (int i = 0; i < 3; i++) {
        int c = tid + i * 256;
        outF[base + c] = (v[i] - mean) * rs * g[c] + bta[c];
    }
}

extern "C" void kernel_launch(void* const* d_in, const int* in_sizes, int n_in,
                              void* d_out, int out_size, void* d_ws, size_t ws_size,
                              hipStream_t stream)
{
    const float* src  = (const float*)d_in[0];
    const float* Wq   = (const float*)d_in[2];  const float* bq = (const float*)d_in[3];
    const float* Wk   = (const float*)d_in[4];  const float* bk = (const float*)d_in[5];
    const float* Wv   = (const float*)d_in[6];  const float* bv = (const float*)d_in[7];
    const float* Wo   = (const float*)d_in[8];  const float* bo = (const float*)d_in[9];
    const float* gam  = (const float*)d_in[10];
    const float* ln1g = (const float*)d_in[11]; const float* ln1b = (const float*)d_in[12];
    const float* ln2g = (const float*)d_in[13]; const float* ln2b = (const float*)d_in[14];
    const float* Wg   = (const float*)d_in[15]; const float* bg = (const float*)d_in[16];
    const float* W1   = (const float*)d_in[17]; const float* b1 = (const float*)d_in[18];
    const float* W2   = (const float*)d_in[19]; const float* b2 = (const float*)d_in[20];
    (void)ws_size; (void)in_sizes; (void)n_in; (void)out_size;

    char* ws = (char*)d_ws;
    // Region B [0, 56,623,104): time-shared.
    //   W1T    at B+0          18,874,368  (written in conversions, read by FF1)
    //   wop    at B+18,874,368 25,165,824  (Wo partials; dead after LN1)
    //   pslab  at B+0          56,623,104  (FF2 partials, 4 slabs x CROWS x 768 f32;
    //                                       written after FF1 -> overlay is safe)
    u16*   W1T  = (u16*)(ws);
    float* wop  = (float*)(ws + 18874368);
    float* pslab= (float*)(ws);
    u16*   W2T  = (u16*)(ws + 56623104);               // 18,874,368 (live through FF2)
    u16*   hb   = (u16*)(ws + 75497472);               // 28,311,552 compact FF1 out [CROWS][3072]
    float* x    = (float*)(ws + 103809024);            //  6,291,456
    u16*   xh   = (u16*)(ws + 110100480);              //  3,145,728
    float* comb = (float*)(ws + 113246208);            //     32,768
    float* bqkv = (float*)(ws + 113278976);            //      9,216
    int*   cnt    = (int*)(ws + 113288192);            //         64
    int*   rowtok = (int*)(ws + 113288256);            //     18,432 (CROWS)
    int*   epack  = (int*)(ws + 113306688);            //      8,192
    int*   tok2row= (int*)(ws + 113323072);            //     16,384  -> total 113,339,456
    // attn-phase aliases inside hb region (all dead before FF1 writes hb)
    char* H = ws + 75497472;
    u16*   Qh     = (u16*)(H);                         //  3,145,728
    u16*   Kh     = (u16*)(H + 3145728);               //  3,145,728
    u16*   VTh    = (u16*)(H + 6291456);               //  3,145,728
    u16*   src_h  = (u16*)(H + 9437184);               //  3,145,728
    u16*   attn_h = (u16*)(H + 12582912);              //  3,145,728
    u16*   WqkvH  = (u16*)(H + 15728640);              //  3,538,944
    u16*   WoH    = (u16*)(H + 19267584);              //  1,179,648 (ends 20,447,232 < 28,311,552)
    const long PZ = (long)NTOK * DD;

    const int DW = DD * DD;  // 589824

    // ---- weight/activation conversions ----
    convert_kernel<<<(NTOK * DD / 8 + 255) / 256, 256, 0, stream>>>(src, src_h, NTOK * DD / 8);
    convert_kernel<<<(DW / 8 + 255) / 256, 256, 0, stream>>>(Wq, WqkvH, DW / 8);
    convert_kernel<<<(DW / 8 + 255) / 256, 256, 0, stream>>>(Wk, WqkvH + DW, DW / 8);
    convert_kernel<<<(DW / 8 + 255) / 256, 256, 0, stream>>>(Wv, WqkvH + 2 * DW, DW / 8);
    convert_kernel<<<(DW / 8 + 255) / 256, 256, 0, stream>>>(Wo, WoH, DW / 8);
    hipMemcpyAsync(bqkv, bq, DD * 4, hipMemcpyDeviceToDevice, stream);
    hipMemcpyAsync(bqkv + DD, bk, DD * 4, hipMemcpyDeviceToDevice, stream);
    hipMemcpyAsync(bqkv + 2 * DD, bv, DD * 4, hipMemcpyDeviceToDevice, stream);
    // W1[e]: [768,3072] -> [3072,768] per expert
    transpose_convert_kernel<<<dim3(FFD / 32, DD / 32, NE), 256, 0, stream>>>(
        W1, W1T, FFD, DD, (long)DD * FFD, (long)FFD * DD);
    // W2[e]: [3072,768] -> per-expert slab W2T[e][n][k], n-stride 3072
    transpose_convert_kernel<<<dim3(DD / 32, FFD / 32, NE), 256, 0, stream>>>(
        W2, W2T, DD, FFD, (long)FFD * DD, (long)FFD * DD);

    // ---- QKV (batched, N=2304) -> bf16 Q,K [B,H,T,64], V^T [B,H,64,T] ----
    gemm_bt_kernel<<<dim3(2304 / 128, NTOK / 128, 1), 256, 0, stream>>>(
        src_h, DD, 0, WqkvH, DD, 0, DD, 0, 0,
        nullptr, Qh, Kh, VTh, 0, 0, bqkv, 0, nullptr, nullptr, nullptr);

    // ---- attention (MFMA) ----
    attn_mfma_kernel<<<dim3(TT / 32, BB * HH), 256, 0, stream>>>(
        Qh, Kh, VTh, gam, attn_h);

    // ---- Wo projection split-K x4 -> fp32 partials in wop ----
    gemm_bt_kernel<<<dim3(DD / 128, NTOK / 128, 4), 256, 0, stream>>>(
        attn_h, DD, 192L, WoH, DD, 192L, 192, 3, 0,
        wop, nullptr, nullptr, nullptr, DD, PZ, nullptr, 0, nullptr, nullptr, nullptr);

    // ---- LN1 + fused gate (no atomics) ----
    ln1_kernel<<<NTOK, 256, 0, stream>>>(
        wop, wop + PZ, wop + 2 * PZ, wop + 3 * PZ, src, bo,
        ln1g, ln1b, Wg, bg, x, xh, comb, epack);

    // ---- deterministic slot assignment (single-block prefix scan) ----
    scan_build_kernel<<<1, 256, 0, stream>>>(epack, cnt, rowtok, tok2row);

    // ---- FF1 compact (top-2 only): gathered A-rows; ~47% fewer live tiles.
    //      Inactive (mt*128 >= cnt[e]) blocks exit immediately. ----
    gemm_bt_kernel<<<dim3(1536, 1, 1), 256, 0, stream>>>(
        xh, DD, 0, W1T, DD, (long)FFD * DD, DD, 2, 1,
        nullptr, hb, nullptr, nullptr, FFD, 0, b1, FFD, rowtok, cnt, comb);

    // ---- FF2 compact: per-expert K=3072 split-K x4 (aZ=bZ=768 k-slice),
    //      partials at compact rows -> 4 slabs; each XCD owns two (e,z)
    //      B-slices (L2-resident) ----
    gemm_bt_kernel<<<dim3(1536, 1, 1), 256, 0, stream>>>(
        hb, FFD, 768L, W2T, FFD, 768L, 768, 4, 3,
        pslab, nullptr, nullptr, nullptr, DD, SLABZ, nullptr, 0, rowtok, cnt, nullptr);

    // ---- LN2 (x + gathered compact partials + comb*b2, then layernorm) ----
    ln2_kernel<<<NTOK, 256, 0, stream>>>(
        x, pslab, tok2row, comb, b2, ln2g, ln2b, (float*)d_out);
}

// Round 3
// 369.531 us; speedup vs baseline: 1.2631x; 1.0776x over previous
//
#include <hip/hip_runtime.h>

typedef unsigned short u16;
typedef short bf16x8 __attribute__((ext_vector_type(8)));
typedef float f32x4 __attribute__((ext_vector_type(4)));

#define BB 2
#define TT 1024
#define DD 768
#define HH 12
#define HD 64
#define FFD 3072
#define NE 4
#define NTOK (BB*TT)
// compact MoE row space: sum_e ceil(cnt[e]/128)*128 <= 4096 + 4*127 = 4604
#define CROWS 4608
#define SLABZ 3538944L   // CROWS*DD elements per FF2 partial slab

#define MFMA16(a, b, c) __builtin_amdgcn_mfma_f32_16x16x32_bf16((a), (b), (c), 0, 0, 0)

#define ASYNC16(gsrc, ldst)                                                    \
    __builtin_amdgcn_global_load_lds(                                          \
        (const __attribute__((address_space(1))) void*)(gsrc),                 \
        (__attribute__((address_space(3))) void*)(ldst), 16, 0, 0)

__device__ __forceinline__ float us2f(u16 u) {
    return __uint_as_float(((unsigned int)u) << 16);
}
__device__ __forceinline__ u16 f2us(float f) {
    unsigned int x = __float_as_uint(f);
    x += 0x7fffu + ((x >> 16) & 1u);
    return (u16)(x >> 16);
}

// ---------------------------------------------------------------------------
// Fused conversion: one launch replaces 5 converts + 3 bias memcpys.
// Segments (grid 1921): [0,196608) src; then 4x73728 for Wq/Wk/Wv/Wo;
// block 1920 copies bq|bk|bv -> bqkv (fp32).
// ---------------------------------------------------------------------------
__global__ __launch_bounds__(256) void convert5_kernel(
    const float* __restrict__ src, const float* __restrict__ wq,
    const float* __restrict__ wk, const float* __restrict__ wv,
    const float* __restrict__ wo,
    const float* __restrict__ bq, const float* __restrict__ bk,
    const float* __restrict__ bv,
    u16* __restrict__ src_h, u16* __restrict__ wqkv_h, u16* __restrict__ wo_h,
    float* __restrict__ bqkv)
{
    const int bid = blockIdx.x, tid = threadIdx.x;
    if (bid == 1920) {
        for (int i = tid; i < 3 * DD; i += 256) {
            float v = (i < DD) ? bq[i] : (i < 2 * DD) ? bk[i - DD] : bv[i - 2 * DD];
            bqkv[i] = v;
        }
        return;
    }
    int i = bid * 256 + tid;
    const float* in; u16* out; int off;
    if (i < 196608) { in = src; out = src_h; off = i; }
    else {
        int j = i - 196608; int w = j / 73728; off = j - w * 73728;
        in = (w == 0) ? wq : (w == 1) ? wk : (w == 2) ? wv : wo;
        out = (w < 3) ? wqkv_h + (size_t)w * (DD * DD) : wo_h;
    }
    const float4* p = reinterpret_cast<const float4*>(in) + (size_t)off * 2;
    float4 a = p[0], b = p[1];
    u16 o[8] = {f2us(a.x), f2us(a.y), f2us(a.z), f2us(a.w),
                f2us(b.x), f2us(b.y), f2us(b.z), f2us(b.w)};
    *reinterpret_cast<uint4*>(out + (size_t)off * 8) = *reinterpret_cast<uint4*>(o);
}

// ---------------------------------------------------------------------------
// Transpose + convert (vectorized): per z, src [.,C] fp32 -> dst bf16 with
// dst[c*dstStride + r]. float4 reads, uint2 (4xbf16) packed writes.
// ---------------------------------------------------------------------------
__global__ __launch_bounds__(256) void transpose_convert_kernel(
    const float* __restrict__ src, u16* __restrict__ dst,
    int C, int dstStride, long srcZ, long dstZ)
{
    __shared__ float tile[32][33];
    const float* s = src + (size_t)blockIdx.z * srcZ;
    u16* d = dst + (size_t)blockIdx.z * dstZ;
    const int c0 = blockIdx.x * 32, r0 = blockIdx.y * 32;
    const int tid = threadIdx.x;
    {
        const int r = tid >> 3, cs = (tid & 7) * 4;
        float4 v = *reinterpret_cast<const float4*>(&s[(size_t)(r0 + r) * C + c0 + cs]);
        tile[r][cs] = v.x; tile[r][cs + 1] = v.y;
        tile[r][cs + 2] = v.z; tile[r][cs + 3] = v.w;
    }
    __syncthreads();
    {
        const int c = tid >> 3, rs = (tid & 7) * 4;
        u16 o[4] = {f2us(tile[rs][c]), f2us(tile[rs + 1][c]),
                    f2us(tile[rs + 2][c]), f2us(tile[rs + 3][c])};
        *reinterpret_cast<uint2*>(&d[(size_t)(c0 + c) * dstStride + r0 + rs]) =
            *reinterpret_cast<uint2*>(o);
    }
}

// ---------------------------------------------------------------------------
// Deterministic compact-slot assignment: single block, Hillis-Steele prefix
// scan of per-thread expert counts over 2048 tokens (8 tokens/thread, 2
// entries each). Zeroes rowtok padding (padding rows keep token 0: valid
// reads, outputs never consumed) and writes cnt.
// ---------------------------------------------------------------------------
__global__ __launch_bounds__(256) void scan_build_kernel(
    const int* __restrict__ epack, int* __restrict__ cnt,
    int* __restrict__ rowtok, int* __restrict__ tok2row)
{
    __shared__ int sc[256][4];
    const int tid = threadIdx.x;
    for (int i = tid; i < CROWS; i += 256) rowtok[i] = 0;
    int ep[8];
    int l0 = 0, l1 = 0, l2 = 0, l3 = 0;
    #pragma unroll
    for (int i = 0; i < 8; i++) {
        const int v = epack[tid * 8 + i];
        ep[i] = v;
        const int a = v & 15, b = (v >> 4) & 15;
        l0 += (a == 0) + (b == 0);
        l1 += (a == 1) + (b == 1);
        l2 += (a == 2) + (b == 2);
        l3 += (a == 3) + (b == 3);
    }
    sc[tid][0] = l0; sc[tid][1] = l1; sc[tid][2] = l2; sc[tid][3] = l3;
    __syncthreads();
    for (int off = 1; off < 256; off <<= 1) {
        int v0 = 0, v1 = 0, v2 = 0, v3 = 0;
        if (tid >= off) {
            v0 = sc[tid - off][0]; v1 = sc[tid - off][1];
            v2 = sc[tid - off][2]; v3 = sc[tid - off][3];
        }
        __syncthreads();
        if (tid >= off) {
            sc[tid][0] += v0; sc[tid][1] += v1;
            sc[tid][2] += v2; sc[tid][3] += v3;
        }
        __syncthreads();
    }
    const int t0 = sc[255][0], t1 = sc[255][1], t2 = sc[255][2], t3 = sc[255][3];
    if (tid == 0) { cnt[0] = t0; cnt[1] = t1; cnt[2] = t2; cnt[3] = t3; }
    const int b1 = (t0 + 127) & ~127;
    const int b2 = b1 + ((t1 + 127) & ~127);
    const int b3 = b2 + ((t2 + 127) & ~127);
    int r0 = sc[tid][0] - l0;
    int r1 = b1 + sc[tid][1] - l1;
    int r2 = b2 + sc[tid][2] - l2;
    int r3 = b3 + sc[tid][3] - l3;
    #pragma unroll
    for (int i = 0; i < 8; i++) {
        const int t = tid * 8 + i;
        const int a = ep[i] & 15, b = (ep[i] >> 4) & 15;
        const int ra = (a == 0) ? r0++ : (a == 1) ? r1++ : (a == 2) ? r2++ : r3++;
        rowtok[ra] = t; tok2row[t * 2] = ra;
        const int rb = (b == 0) ? r0++ : (b == 1) ? r1++ : (b == 2) ? r2++ : r3++;
        rowtok[rb] = t; tok2row[t * 2 + 1] = rb;
    }
}

// ---------------------------------------------------------------------------
// bf16 MFMA GEMM: C[M,N] = A[M,K] * Bt[N,K]^T  (both row-major, K-contiguous)
// 128x128 tile, 4 waves, 16x16x32 MFMA, fp32 accum.
// BK=64 K-loop (half the barrier pairs of BK=32): LDS [128][64] u16 per
// operand (32 KB total). Staging: 8x global_load_lds 16B; XOR col-group
// swizzle (group ^= row&7) applied on the GLOBAL source side (LDS dest must
// stay linear), mirrored on the fragment read -> conflict-free b128 reads.
// modes:
//  0 QKV:  y=acc+biasF[n]; bf16 scatter: Q,K -> [B,H,T,64]; V -> VT [B,H,64,T]
//  2 FF1 (COMPACT): A-rows gathered via rowtok[baseE + tilerow]; active iff
//          by*128 < cnt[e]; y=relu(acc+b1[e,n])*comb[tok,e] -> hb[crow][FFD]
//  3 Wo split-K partial: outF + z*cZ, plain fp32 store
//  4 FF2 (COMPACT): A=hb compact rows, B=W2T expert slab + k-slice z;
//          partial fp32 -> pslab + z*cZ at compact rows
// swz: 0 = 3D grid as-is
//  1: FF1 flat 1536: xcd=fid&7; r=fid>>3; ne=xcd*12+(r%12); by=r/12;
//     bx=ne%24; e=ne/24   -> each XCD owns 12 (n,e) B-tiles (L2-resident)
//  3: FF2 flat 1536: xcd=fid&7; r=fid>>3; half=r>=96; ez=xcd*2+half;
//     e=ez>>2; z=ez&3; rr=r-96*half; bx=rr%6; by=rr/6
// ---------------------------------------------------------------------------
__global__ __launch_bounds__(256) void gemm_bt_kernel(
    const u16* __restrict__ A, int lda, long aZ,
    const u16* __restrict__ Bt, int ldb, long bZ,
    int K, int mode, int swz,
    float* __restrict__ outF, u16* __restrict__ outH,
    u16* __restrict__ outH2, u16* __restrict__ outH3,
    int ldc, long cZ,
    const float* __restrict__ biasF, int biasZ,
    const int* __restrict__ rowtok, const int* __restrict__ cntp,
    const float* __restrict__ comb)
{
    __shared__ __align__(16) u16 As[128 * 64];
    __shared__ __align__(16) u16 Bs[128 * 64];
    const int tid = threadIdx.x;
    int bx, by, z, e = 0, baseE = 0;
    if (swz == 3) {
        const int fid = blockIdx.x;
        const int xcd = fid & 7; int r = fid >> 3;
        const int half = (r >= 96) ? 1 : 0; r -= half * 96;
        bx = r % 6; by = r / 6;
        const int ez = xcd * 2 + half; e = ez >> 2; z = ez & 3;
    } else if (swz == 1) {
        const int fid = blockIdx.x;
        const int xcd = fid & 7; const int r = fid >> 3;
        const int ne = xcd * 12 + (r % 12);
        by = r / 12; bx = ne % 24; e = ne / 24; z = e;
    } else {
        bx = blockIdx.x; by = blockIdx.y; z = blockIdx.z;
    }
    if (mode == 2 || mode == 4) {
        const int q0 = (cntp[0] + 127) & ~127;
        const int q1 = (cntp[1] + 127) & ~127;
        const int q2 = (cntp[2] + 127) & ~127;
        baseE = (e > 0 ? q0 : 0) + (e > 1 ? q1 : 0) + (e > 2 ? q2 : 0);
        if (by * 128 >= cntp[e]) return;   // uniform per block: safe early-exit
    }
    const int m0 = by * 128, n0 = bx * 128;
    const u16* Ab = A + (size_t)z * aZ;
    const u16* Bb = Bt + (size_t)z * bZ;
    if (mode == 4) {
        Ab += (size_t)baseE * lda;
        Bb += (size_t)e * ((size_t)DD * FFD);
    }

    const int wave = tid >> 6, lane = tid & 63;
    const int wm = (wave & 1) * 64, wn = (wave >> 1) * 64;
    const int fm = lane & 15;
    const int g  = lane >> 4;

    // staging: wave w covers tile rows [w*32, w*32+32); 4 instrs per operand,
    // instr i covers rows +[i*8, i*8+8). Lane: row lr8=lane>>3, col group
    // (lane&7), sourcing global group (lane&7)^lr8 (XOR involution).
    const int lr8 = lane >> 3;
    const int cg  = ((lane & 7) ^ lr8) * 8;   // swizzled global col (u16)
    const u16 *aG[4], *bG[4];
    u16 *aL[4], *bL[4];
    #pragma unroll
    for (int i = 0; i < 4; i++) {
        const int rr = wave * 32 + i * 8 + lr8;
        int arow;
        if (mode == 2) arow = rowtok[baseE + m0 + rr];
        else           arow = m0 + rr;
        aG[i] = Ab + (size_t)arow * lda + cg;
        bG[i] = Bb + (size_t)(n0 + rr) * ldb + cg;
        aL[i] = &As[(wave * 32 + i * 8) * 64];
        bL[i] = &Bs[(wave * 32 + i * 8) * 64];
    }

    // fragment reads: global col g*8 + ks*32 lives at LDS group
    // ((g + ks*4) ^ (row&7)); row&7 == fm&7 for rows wm+i*16+fm
    const int c0 = ((g    ) ^ (fm & 7)) * 8;
    const int c1 = ((g + 4) ^ (fm & 7)) * 8;
    const u16* pa[4]; const u16* pb[4];
    #pragma unroll
    for (int i = 0; i < 4; i++) {
        pa[i] = &As[(wm + i * 16 + fm) * 64];
        pb[i] = &Bs[(wn + i * 16 + fm) * 64];
    }

    f32x4 acc[4][4] = {};

    for (int k0 = 0; k0 < K; k0 += 64) {
        #pragma unroll
        for (int i = 0; i < 4; i++) ASYNC16(aG[i] + k0, aL[i]);
        #pragma unroll
        for (int i = 0; i < 4; i++) ASYNC16(bG[i] + k0, bL[i]);
        __syncthreads();
        #pragma unroll
        for (int ks = 0; ks < 2; ks++) {
            const int cc = ks ? c1 : c0;
            bf16x8 af[4], bf[4];
            #pragma unroll
            for (int i = 0; i < 4; i++)
                af[i] = *reinterpret_cast<const bf16x8*>(pa[i] + cc);
            #pragma unroll
            for (int j = 0; j < 4; j++)
                bf[j] = *reinterpret_cast<const bf16x8*>(pb[j] + cc);
            #pragma unroll
            for (int i = 0; i < 4; i++)
                #pragma unroll
                for (int j = 0; j < 4; j++)
                    acc[i][j] = MFMA16(af[i], bf[j], acc[i][j]);
        }
        __syncthreads();
    }

    // C/D layout: col = lane&15, row = (lane>>4)*4 + reg   [m89-verified]
    const int cn = lane & 15, cr = (lane >> 4) * 4;

    if (mode == 2) {
        // LDS-repacked epilogue: 4 passes x 32 rows, dwordx4 coalesced stores
        u16* Cs = As;
        #pragma unroll
        for (int i = 0; i < 4; i++) {
            if (i) __syncthreads();
            int tokr[4]; float combr[4];
            #pragma unroll
            for (int r = 0; r < 4; r++)
                tokr[r] = rowtok[baseE + m0 + wm + i * 16 + cr + r];
            #pragma unroll
            for (int r = 0; r < 4; r++)
                combr[r] = comb[(size_t)tokr[r] * NE + z];
            #pragma unroll
            for (int j = 0; j < 4; j++) {
                const int n = n0 + wn + j * 16 + cn;
                const float bias = biasF[(size_t)z * biasZ + n];
                #pragma unroll
                for (int r = 0; r < 4; r++) {
                    float y = fmaxf(acc[i][j][r] + bias, 0.f) * combr[r];
                    Cs[((wave & 1) * 16 + cr + r) * 128 + wn + j * 16 + cn] = f2us(y);
                }
            }
            __syncthreads();
            const int lr2 = tid >> 3, c2 = (tid & 7) * 16;
            const int m2 = m0 + (lr2 >> 4) * 64 + i * 16 + (lr2 & 15);
            u16* dst = outH + (size_t)(baseE + m2) * ldc + n0 + c2;
            *reinterpret_cast<uint4*>(dst) =
                *reinterpret_cast<const uint4*>(&Cs[lr2 * 128 + c2]);
            *reinterpret_cast<uint4*>(dst + 8) =
                *reinterpret_cast<const uint4*>(&Cs[lr2 * 128 + c2 + 8]);
        }
        return;
    }

    #pragma unroll
    for (int i = 0; i < 4; i++) {
        #pragma unroll
        for (int j = 0; j < 4; j++) {
            const int n = n0 + wn + j * 16 + cn;
            #pragma unroll
            for (int r = 0; r < 4; r++) {
                const int m = m0 + wm + i * 16 + cr + r;
                float y = acc[i][j][r];
                if (mode == 0) {
                    y += biasF[n];
                    int which = (n >= 1536) ? 2 : (n >= 768 ? 1 : 0);
                    int nn = n - which * 768;
                    int bb = m >> 10, t = m & 1023;
                    int hh = nn >> 6, d = nn & 63;
                    if (which == 0)
                        outH[(((size_t)(bb * HH + hh) * TT + t) << 6) + d] = f2us(y);
                    else if (which == 1)
                        outH2[(((size_t)(bb * HH + hh) * TT + t) << 6) + d] = f2us(y);
                    else
                        outH3[(((size_t)(bb * HH + hh) * HD + d) << 10) + t] = f2us(y);
                } else {  // mode 3 (baseE=0) and mode 4 (compact rows)
                    float* basep = outF + (size_t)z * cZ;
                    basep[(size_t)(baseE + m) * ldc + n] = y;
                }
            }
        }
    }
}

// ---------------------------------------------------------------------------
// MFMA attention. Block = (qt 32 rows, b*12+h). 4 waves.
// Phase 1: S[32][1024] in accumulators (wave w covers cols w*256..+256).
// zscore is scale-invariant: a = gamma/(std_ddof1(S)+EPS_Z/0.125); shift
// cancels in softmax; cm = max(a*S) for stability.
// Phase 2: P bf16 in LDS; O = P*V via MFMA (V pre-transposed [B,H,64,T]).
// ---------------------------------------------------------------------------
#define PSTR 1032  // u16 stride: byte stride 2064 (16B aligned), dw 516 ≡ 4 mod 8 -> conflict-free b128
__global__ __launch_bounds__(256, 2) void attn_mfma_kernel(
    const u16* __restrict__ Qh, const u16* __restrict__ Kh,
    const u16* __restrict__ VT, const float* __restrict__ gamma_p,
    u16* __restrict__ attn_out)
{
    __shared__ __align__(16) u16 P[32 * PSTR];
    __shared__ float wred[4][32][4];
    __shared__ float dred[4][32];
    __shared__ float aArr[32], cmArr[32], dinvArr[32];

    const int qt = blockIdx.x, bh = blockIdx.y;
    const int b = bh / HH, h = bh - b * HH;
    const int tid = threadIdx.x, wave = tid >> 6, lane = tid & 63;
    const int g = lane >> 4, fm = lane & 15;
    const float gamma = gamma_p[0];
    const int m0 = qt * 32;
    const u16* Qp = Qh + (size_t)bh * TT * HD;
    const u16* Kp = Kh + (size_t)bh * TT * HD;
    const u16* Vp = VT + (size_t)bh * HD * TT;

    bf16x8 af[2][2];
    #pragma unroll
    for (int mi = 0; mi < 2; mi++)
        #pragma unroll
        for (int ks = 0; ks < 2; ks++)
            af[mi][ks] = *reinterpret_cast<const bf16x8*>(
                Qp + (size_t)(m0 + mi * 16 + fm) * HD + ks * 32 + g * 8);

    const int n0w = wave * 256;
    f32x4 acc[16][2] = {};
    #pragma unroll
    for (int nj = 0; nj < 16; nj++) {
        const u16* kp = Kp + (size_t)(n0w + nj * 16 + fm) * HD + g * 8;
        bf16x8 b0 = *reinterpret_cast<const bf16x8*>(kp);
        bf16x8 b1 = *reinterpret_cast<const bf16x8*>(kp + 32);
        acc[nj][0] = MFMA16(af[0][0], b0, acc[nj][0]);
        acc[nj][0] = MFMA16(af[0][1], b1, acc[nj][0]);
        acc[nj][1] = MFMA16(af[1][0], b0, acc[nj][1]);
        acc[nj][1] = MFMA16(af[1][1], b1, acc[nj][1]);
    }

    #pragma unroll
    for (int mi = 0; mi < 2; mi++) {
        #pragma unroll
        for (int r = 0; r < 4; r++) {
            float s1 = 0.f, s2 = 0.f, mx = -3.4e38f, mn = 3.4e38f;
            #pragma unroll
            for (int nj = 0; nj < 16; nj++) {
                float v = acc[nj][mi][r];
                s1 += v; s2 = fmaf(v, v, s2);
                mx = fmaxf(mx, v); mn = fminf(mn, v);
            }
            #pragma unroll
            for (int msk = 1; msk < 16; msk <<= 1) {
                s1 += __shfl_xor(s1, msk);
                s2 += __shfl_xor(s2, msk);
                mx = fmaxf(mx, __shfl_xor(mx, msk));
                mn = fminf(mn, __shfl_xor(mn, msk));
            }
            if (fm == 0) {
                int row = mi * 16 + g * 4 + r;
                wred[wave][row][0] = s1; wred[wave][row][1] = s2;
                wred[wave][row][2] = mx; wred[wave][row][3] = mn;
            }
        }
    }
    __syncthreads();
    if (tid < 32) {
        float s1 = 0.f, s2 = 0.f, mx = -3.4e38f, mn = 3.4e38f;
        #pragma unroll
        for (int w = 0; w < 4; w++) {
            s1 += wred[w][tid][0]; s2 += wred[w][tid][1];
            mx = fmaxf(mx, wred[w][tid][2]); mn = fminf(mn, wred[w][tid][3]);
        }
        float var = (s2 - s1 * s1 * (1.f / TT)) * (1.f / (TT - 1));
        var = fmaxf(var, 0.f);
        float a = gamma / (sqrtf(var) + 8e-5f);
        aArr[tid] = a;
        cmArr[tid] = (a >= 0.f) ? a * mx : a * mn;
    }
    __syncthreads();

    #pragma unroll
    for (int mi = 0; mi < 2; mi++) {
        #pragma unroll
        for (int r = 0; r < 4; r++) {
            const int row = mi * 16 + g * 4 + r;
            const float a = aArr[row], cm = cmArr[row];
            float dp = 0.f;
            #pragma unroll
            for (int nj = 0; nj < 16; nj++) {
                float p = __expf(fmaf(a, acc[nj][mi][r], -cm));
                u16 pb = f2us(p);
                dp += us2f(pb);
                P[row * PSTR + n0w + nj * 16 + fm] = pb;
            }
            #pragma unroll
            for (int msk = 1; msk < 16; msk <<= 1) dp += __shfl_xor(dp, msk);
            if (fm == 0) dred[wave][row] = dp;
        }
    }
    __syncthreads();
    if (tid < 32)
        dinvArr[tid] = 1.f / (dred[0][tid] + dred[1][tid] + dred[2][tid] + dred[3][tid]);
    __syncthreads();

    f32x4 oacc[2] = {};
    #pragma unroll 4
    for (int ks = 0; ks < 32; ks++) {
        bf16x8 bv = *reinterpret_cast<const bf16x8*>(
            Vp + (size_t)(wave * 16 + fm) * TT + ks * 32 + g * 8);
        bf16x8 a0 = *reinterpret_cast<const bf16x8*>(&P[(size_t)fm * PSTR + ks * 32 + g * 8]);
        bf16x8 a1 = *reinterpret_cast<const bf16x8*>(&P[(size_t)(16 + fm) * PSTR + ks * 32 + g * 8]);
        oacc[0] = MFMA16(a0, bv, oacc[0]);
        oacc[1] = MFMA16(a1, bv, oacc[1]);
    }
    #pragma unroll
    for (int mi = 0; mi < 2; mi++) {
        #pragma unroll
        for (int r = 0; r < 4; r++) {
            int row = mi * 16 + g * 4 + r;
            int t = m0 + row;
            attn_out[((size_t)(b * TT + t)) * DD + h * HD + wave * 16 + fm] =
                f2us(oacc[mi][r] * dinvArr[row]);
        }
    }
}

// ---------------------------------------------------------------------------
// LN1 fused + gate: r1 = p0+p1+p2+p3 (Wo split-K partials) + src + bo;
// layernorm -> x fp32 + xh bf16. Gate fused on the post-LN values held in
// registers: g[e] = sum_c x[c]*Wg[e,c]; thread-0 softmax/top-2 -> comb,
// epack[t] = e1 | (e2<<4). No atomics (slot assignment in scan_build).
// ---------------------------------------------------------------------------
__global__ __launch_bounds__(256) void ln1_kernel(
    const float* __restrict__ p0, const float* __restrict__ p1,
    const float* __restrict__ p2, const float* __restrict__ p3,
    const float* __restrict__ src, const float* __restrict__ bo,
    const float* __restrict__ g, const float* __restrict__ bta,
    const float* __restrict__ Wg, const float* __restrict__ bg,
    float* __restrict__ outF, u16* __restrict__ outH,
    float* __restrict__ comb, int* __restrict__ epack)
{
    const int row = blockIdx.x, tid = threadIdx.x;
    __shared__ float red[256];
    __shared__ float gred[4][4];
    const size_t base = (size_t)row * DD;
    float v[3];
    #pragma unroll
    for (int i = 0; i < 3; i++) {
        int c = tid + i * 256;
        v[i] = p0[base + c] + p1[base + c] + p2[base + c] + p3[base + c]
             + src[base + c] + bo[c];
    }
    float s = v[0] + v[1] + v[2];
    red[tid] = s; __syncthreads();
    #pragma unroll
    for (int o = 128; o > 0; o >>= 1) { if (tid < o) red[tid] += red[tid + o]; __syncthreads(); }
    const float mean = red[0] * (1.f / 768.f);
    __syncthreads();
    float qv = 0.f;
    #pragma unroll
    for (int i = 0; i < 3; i++) { float d = v[i] - mean; qv += d * d; }
    red[tid] = qv; __syncthreads();
    #pragma unroll
    for (int o = 128; o > 0; o >>= 1) { if (tid < o) red[tid] += red[tid + o]; __syncthreads(); }
    const float var = red[0] * (1.f / 768.f);
    const float rs = rsqrtf(var + 1e-5f);
    float ga0 = 0.f, ga1 = 0.f, ga2 = 0.f, ga3 = 0.f;
    #pragma unroll
    for (int i = 0; i < 3; i++) {
        int c = tid + i * 256;
        float o = (v[i] - mean) * rs * g[c] + bta[c];
        outF[base + c] = o;
        outH[base + c] = f2us(o);
        ga0 = fmaf(o, Wg[c], ga0);
        ga1 = fmaf(o, Wg[DD + c], ga1);
        ga2 = fmaf(o, Wg[2 * DD + c], ga2);
        ga3 = fmaf(o, Wg[3 * DD + c], ga3);
    }
    #pragma unroll
    for (int off = 32; off > 0; off >>= 1) {
        ga0 += __shfl_down(ga0, off, 64);
        ga1 += __shfl_down(ga1, off, 64);
        ga2 += __shfl_down(ga2, off, 64);
        ga3 += __shfl_down(ga3, off, 64);
    }
    const int wave = tid >> 6, lane = tid & 63;
    if (lane == 0) {
        gred[wave][0] = ga0; gred[wave][1] = ga1;
        gred[wave][2] = ga2; gred[wave][3] = ga3;
    }
    __syncthreads();
    if (tid == 0) {
        float gg[NE];
        #pragma unroll
        for (int e = 0; e < NE; e++)
            gg[e] = gred[0][e] + gred[1][e] + gred[2][e] + gred[3][e] + bg[e];
        float m = -1e30f;
        #pragma unroll
        for (int e = 0; e < NE; e++) m = fmaxf(m, gg[e]);
        float ex[NE], ssum = 0.f;
        #pragma unroll
        for (int e = 0; e < NE; e++) { ex[e] = __expf(gg[e] - m); ssum += ex[e]; }
        #pragma unroll
        for (int e = 0; e < NE; e++) ex[e] /= ssum;
        int e1 = 0;
        #pragma unroll
        for (int e = 1; e < NE; e++) if (ex[e] > ex[e1]) e1 = e;
        int e2 = -1;
        #pragma unroll
        for (int e = 0; e < NE; e++) if (e != e1 && (e2 < 0 || ex[e] > ex[e2])) e2 = e;
        float c[NE] = {0.f, 0.f, 0.f, 0.f};
        c[e1] = ex[e1]; c[e2] = ex[e2];
        #pragma unroll
        for (int e = 0; e < NE; e++) comb[(size_t)row * NE + e] = c[e];
        epack[row] = e1 | (e2 << 4);
    }
}

// ---------------------------------------------------------------------------
// LN2 (compact): t = x + sum_z sum_{i=0,1} pslab[z][tok2row[t,i]] + comb*b2;
// layernorm -> out. Gathered rows are contiguous (coalesced within a row).
// ---------------------------------------------------------------------------
__global__ __launch_bounds__(256) void ln2_kernel(
    const float* __restrict__ x, const float* __restrict__ pslab,
    const int* __restrict__ tok2row,
    const float* __restrict__ comb, const float* __restrict__ b2,
    const float* __restrict__ g, const float* __restrict__ bta,
    float* __restrict__ outF)
{
    const int row = blockIdx.x, tid = threadIdx.x;
    __shared__ float red[256];
    const size_t base = (size_t)row * DD;
    const int r0 = tok2row[row * 2], r1 = tok2row[row * 2 + 1];
    const float* q0 = pslab + (size_t)r0 * DD;
    const float* q1 = pslab + (size_t)r1 * DD;
    const float c0 = comb[row * NE + 0], c1 = comb[row * NE + 1];
    const float c2 = comb[row * NE + 2], c3 = comb[row * NE + 3];
    float v[3];
    #pragma unroll
    for (int i = 0; i < 3; i++) {
        int c = tid + i * 256;
        float t = x[base + c];
        t += q0[c] + q0[SLABZ + c] + q0[2 * SLABZ + c] + q0[3 * SLABZ + c];
        t += q1[c] + q1[SLABZ + c] + q1[2 * SLABZ + c] + q1[3 * SLABZ + c];
        t = fmaf(c0, b2[c], t);
        t = fmaf(c1, b2[DD + c], t);
        t = fmaf(c2, b2[2 * DD + c], t);
        t = fmaf(c3, b2[3 * DD + c], t);
        v[i] = t;
    }
    float s = v[0] + v[1] + v[2];
    red[tid] = s; __syncthreads();
    #pragma unroll
    for (int o = 128; o > 0; o >>= 1) { if (tid < o) red[tid] += red[tid + o]; __syncthreads(); }
    const float mean = red[0] * (1.f / 768.f);
    __syncthreads();
    float qv = 0.f;
    #pragma unroll
    for (int i = 0; i < 3; i++) { float d = v[i] - mean; qv += d * d; }
    red[tid] = qv; __syncthreads();
    #pragma unroll
    for (int o = 128; o > 0; o >>= 1) { if (tid < o) red[tid] += red[tid + o]; __syncthreads(); }
    const float var = red[0] * (1.f / 768.f);
    const float rs = rsqrtf(var + 1e-5f);
    #pragma unroll
    for (int i = 0; i < 3; i++) {
        int c = tid + i * 256;
        outF[base + c] = (v[i] - mean) * rs * g[c] + bta[c];
    }
}

extern "C" void kernel_launch(void* const* d_in, const int* in_sizes, int n_in,
                              void* d_out, int out_size, void* d_ws, size_t ws_size,
                              hipStream_t stream)
{
    const float* src  = (const float*)d_in[0];
    const float* Wq   = (const float*)d_in[2];  const float* bq = (const float*)d_in[3];
    const float* Wk   = (const float*)d_in[4];  const float* bk = (const float*)d_in[5];
    const float* Wv   = (const float*)d_in[6];  const float* bv = (const float*)d_in[7];
    const float* Wo   = (const float*)d_in[8];  const float* bo = (const float*)d_in[9];
    const float* gam  = (const float*)d_in[10];
    const float* ln1g = (const float*)d_in[11]; const float* ln1b = (const float*)d_in[12];
    const float* ln2g = (const float*)d_in[13]; const float* ln2b = (const float*)d_in[14];
    const float* Wg   = (const float*)d_in[15]; const float* bg = (const float*)d_in[16];
    const float* W1   = (const float*)d_in[17]; const float* b1 = (const float*)d_in[18];
    const float* W2   = (const float*)d_in[19]; const float* b2 = (const float*)d_in[20];
    (void)ws_size; (void)in_sizes; (void)n_in; (void)out_size;

    char* ws = (char*)d_ws;
    // Region B [0, 56,623,104): time-shared.
    //   W1T    at B+0          18,874,368  (written in conversions, read by FF1)
    //   wop    at B+18,874,368 25,165,824  (Wo partials; dead after LN1)
    //   pslab  at B+0          56,623,104  (FF2 partials, 4 slabs x CROWS x 768 f32;
    //                                       written after FF1 -> overlay is safe)
    u16*   W1T  = (u16*)(ws);
    float* wop  = (float*)(ws + 18874368);
    float* pslab= (float*)(ws);
    u16*   W2T  = (u16*)(ws + 56623104);               // 18,874,368 (live through FF2)
    u16*   hb   = (u16*)(ws + 75497472);               // 28,311,552 compact FF1 out [CROWS][3072]
    float* x    = (float*)(ws + 103809024);            //  6,291,456
    u16*   xh   = (u16*)(ws + 110100480);              //  3,145,728
    float* comb = (float*)(ws + 113246208);            //     32,768
    float* bqkv = (float*)(ws + 113278976);            //      9,216
    int*   cnt    = (int*)(ws + 113288192);            //         64
    int*   rowtok = (int*)(ws + 113288256);            //     18,432 (CROWS)
    int*   epack  = (int*)(ws + 113306688);            //      8,192
    int*   tok2row= (int*)(ws + 113323072);            //     16,384  -> total 113,339,456
    // attn-phase aliases inside hb region (all dead before FF1 writes hb)
    char* H = ws + 75497472;
    u16*   Qh     = (u16*)(H);                         //  3,145,728
    u16*   Kh     = (u16*)(H + 3145728);               //  3,145,728
    u16*   VTh    = (u16*)(H + 6291456);               //  3,145,728
    u16*   src_h  = (u16*)(H + 9437184);               //  3,145,728
    u16*   attn_h = (u16*)(H + 12582912);              //  3,145,728
    u16*   WqkvH  = (u16*)(H + 15728640);              //  3,538,944
    u16*   WoH    = (u16*)(H + 19267584);              //  1,179,648 (ends 20,447,232 < 28,311,552)
    const long PZ = (long)NTOK * DD;

    // ---- fused conversions (1 launch: src + 4 weights + 3 biases) ----
    convert5_kernel<<<1921, 256, 0, stream>>>(
        src, Wq, Wk, Wv, Wo, bq, bk, bv, src_h, WqkvH, WoH, bqkv);
    // W1[e]: [768,3072] -> [3072,768] per expert
    transpose_convert_kernel<<<dim3(FFD / 32, DD / 32, NE), 256, 0, stream>>>(
        W1, W1T, FFD, DD, (long)DD * FFD, (long)FFD * DD);
    // W2[e]: [3072,768] -> per-expert slab W2T[e][n][k], n-stride 3072
    transpose_convert_kernel<<<dim3(DD / 32, FFD / 32, NE), 256, 0, stream>>>(
        W2, W2T, DD, FFD, (long)FFD * DD, (long)FFD * DD);

    // ---- QKV (batched, N=2304) -> bf16 Q,K [B,H,T,64], V^T [B,H,64,T] ----
    gemm_bt_kernel<<<dim3(2304 / 128, NTOK / 128, 1), 256, 0, stream>>>(
        src_h, DD, 0, WqkvH, DD, 0, DD, 0, 0,
        nullptr, Qh, Kh, VTh, 0, 0, bqkv, 0, nullptr, nullptr, nullptr);

    // ---- attention (MFMA) ----
    attn_mfma_kernel<<<dim3(TT / 32, BB * HH), 256, 0, stream>>>(
        Qh, Kh, VTh, gam, attn_h);

    // ---- Wo projection split-K x4 -> fp32 partials in wop ----
    gemm_bt_kernel<<<dim3(DD / 128, NTOK / 128, 4), 256, 0, stream>>>(
        attn_h, DD, 192L, WoH, DD, 192L, 192, 3, 0,
        wop, nullptr, nullptr, nullptr, DD, PZ, nullptr, 0, nullptr, nullptr, nullptr);

    // ---- LN1 + fused gate (no atomics) ----
    ln1_kernel<<<NTOK, 256, 0, stream>>>(
        wop, wop + PZ, wop + 2 * PZ, wop + 3 * PZ, src, bo,
        ln1g, ln1b, Wg, bg, x, xh, comb, epack);

    // ---- deterministic slot assignment (single-block prefix scan) ----
    scan_build_kernel<<<1, 256, 0, stream>>>(epack, cnt, rowtok, tok2row);

    // ---- FF1 compact (top-2 only): gathered A-rows; ~47% fewer live tiles ----
    gemm_bt_kernel<<<dim3(1536, 1, 1), 256, 0, stream>>>(
        xh, DD, 0, W1T, DD, (long)FFD * DD, DD, 2, 1,
        nullptr, hb, nullptr, nullptr, FFD, 0, b1, FFD, rowtok, cnt, comb);

    // ---- FF2 compact: per-expert K=3072 split-K x4 (aZ=bZ=768 k-slice),
    //      partials at compact rows -> 4 slabs; each XCD owns two (e,z)
    //      B-slices (L2-resident) ----
    gemm_bt_kernel<<<dim3(1536, 1, 1), 256, 0, stream>>>(
        hb, FFD, 768L, W2T, FFD, 768L, 768, 4, 3,
        pslab, nullptr, nullptr, nullptr, DD, SLABZ, nullptr, 0, rowtok, cnt, nullptr);

    // ---- LN2 (x + gathered compact partials + comb*b2, then layernorm) ----
    ln2_kernel<<<NTOK, 256, 0, stream>>>(
        x, pslab, tok2row, comb, b2, ln2g, ln2b, (float*)d_out);
}

// Round 4
// 343.589 us; speedup vs baseline: 1.3585x; 1.0755x over previous
//
#include <hip/hip_runtime.h>

typedef unsigned short u16;
typedef short bf16x8 __attribute__((ext_vector_type(8)));
typedef float f32x4 __attribute__((ext_vector_type(4)));

#define BB 2
#define TT 1024
#define DD 768
#define HH 12
#define HD 64
#define FFD 3072
#define NE 4
#define NTOK (BB*TT)
// compact MoE row space: sum_e ceil(cnt[e]/128)*128 <= 4096 + 4*127 = 4604
#define CROWS 4608
#define SLABZ 3538944L   // CROWS*DD elements per FF2 partial slab

#define MFMA16(a, b, c) __builtin_amdgcn_mfma_f32_16x16x32_bf16((a), (b), (c), 0, 0, 0)

#define ASYNC16(gsrc, ldst)                                                    \
    __builtin_amdgcn_global_load_lds(                                          \
        (const __attribute__((address_space(1))) void*)(gsrc),                 \
        (__attribute__((address_space(3))) void*)(ldst), 16, 0, 0)

__device__ __forceinline__ float us2f(u16 u) {
    return __uint_as_float(((unsigned int)u) << 16);
}
__device__ __forceinline__ u16 f2us(float f) {
    unsigned int x = __float_as_uint(f);
    x += 0x7fffu + ((x >> 16) & 1u);
    return (u16)(x >> 16);
}

// ---------------------------------------------------------------------------
// Fused conversion: one launch replaces 5 converts + 3 bias memcpys.
// ---------------------------------------------------------------------------
__global__ __launch_bounds__(256) void convert5_kernel(
    const float* __restrict__ src, const float* __restrict__ wq,
    const float* __restrict__ wk, const float* __restrict__ wv,
    const float* __restrict__ wo,
    const float* __restrict__ bq, const float* __restrict__ bk,
    const float* __restrict__ bv,
    u16* __restrict__ src_h, u16* __restrict__ wqkv_h, u16* __restrict__ wo_h,
    float* __restrict__ bqkv)
{
    const int bid = blockIdx.x, tid = threadIdx.x;
    if (bid == 1920) {
        for (int i = tid; i < 3 * DD; i += 256) {
            float v = (i < DD) ? bq[i] : (i < 2 * DD) ? bk[i - DD] : bv[i - 2 * DD];
            bqkv[i] = v;
        }
        return;
    }
    int i = bid * 256 + tid;
    const float* in; u16* out; int off;
    if (i < 196608) { in = src; out = src_h; off = i; }
    else {
        int j = i - 196608; int w = j / 73728; off = j - w * 73728;
        in = (w == 0) ? wq : (w == 1) ? wk : (w == 2) ? wv : wo;
        out = (w < 3) ? wqkv_h + (size_t)w * (DD * DD) : wo_h;
    }
    const float4* p = reinterpret_cast<const float4*>(in) + (size_t)off * 2;
    float4 a = p[0], b = p[1];
    u16 o[8] = {f2us(a.x), f2us(a.y), f2us(a.z), f2us(a.w),
                f2us(b.x), f2us(b.y), f2us(b.z), f2us(b.w)};
    *reinterpret_cast<uint4*>(out + (size_t)off * 8) = *reinterpret_cast<uint4*>(o);
}

// ---------------------------------------------------------------------------
// Transpose + convert (vectorized): per z, src [.,C] fp32 -> dst bf16 with
// dst[c*dstStride + r]. float4 reads, uint2 (4xbf16) packed writes.
// ---------------------------------------------------------------------------
__global__ __launch_bounds__(256) void transpose_convert_kernel(
    const float* __restrict__ src, u16* __restrict__ dst,
    int C, int dstStride, long srcZ, long dstZ)
{
    __shared__ float tile[32][33];
    const float* s = src + (size_t)blockIdx.z * srcZ;
    u16* d = dst + (size_t)blockIdx.z * dstZ;
    const int c0 = blockIdx.x * 32, r0 = blockIdx.y * 32;
    const int tid = threadIdx.x;
    {
        const int r = tid >> 3, cs = (tid & 7) * 4;
        float4 v = *reinterpret_cast<const float4*>(&s[(size_t)(r0 + r) * C + c0 + cs]);
        tile[r][cs] = v.x; tile[r][cs + 1] = v.y;
        tile[r][cs + 2] = v.z; tile[r][cs + 3] = v.w;
    }
    __syncthreads();
    {
        const int c = tid >> 3, rs = (tid & 7) * 4;
        u16 o[4] = {f2us(tile[rs][c]), f2us(tile[rs + 1][c]),
                    f2us(tile[rs + 2][c]), f2us(tile[rs + 3][c])};
        *reinterpret_cast<uint2*>(&d[(size_t)(c0 + c) * dstStride + r0 + rs]) =
            *reinterpret_cast<uint2*>(o);
    }
}

// ---------------------------------------------------------------------------
// Deterministic compact-slot assignment: single block, Hillis-Steele prefix
// scan over 2048 tokens (8 tokens/thread, 2 entries each).
// ---------------------------------------------------------------------------
__global__ __launch_bounds__(256) void scan_build_kernel(
    const int* __restrict__ epack, int* __restrict__ cnt,
    int* __restrict__ rowtok, int* __restrict__ tok2row)
{
    __shared__ int sc[256][4];
    const int tid = threadIdx.x;
    for (int i = tid; i < CROWS; i += 256) rowtok[i] = 0;
    int ep[8];
    int l0 = 0, l1 = 0, l2 = 0, l3 = 0;
    #pragma unroll
    for (int i = 0; i < 8; i++) {
        const int v = epack[tid * 8 + i];
        ep[i] = v;
        const int a = v & 15, b = (v >> 4) & 15;
        l0 += (a == 0) + (b == 0);
        l1 += (a == 1) + (b == 1);
        l2 += (a == 2) + (b == 2);
        l3 += (a == 3) + (b == 3);
    }
    sc[tid][0] = l0; sc[tid][1] = l1; sc[tid][2] = l2; sc[tid][3] = l3;
    __syncthreads();
    for (int off = 1; off < 256; off <<= 1) {
        int v0 = 0, v1 = 0, v2 = 0, v3 = 0;
        if (tid >= off) {
            v0 = sc[tid - off][0]; v1 = sc[tid - off][1];
            v2 = sc[tid - off][2]; v3 = sc[tid - off][3];
        }
        __syncthreads();
        if (tid >= off) {
            sc[tid][0] += v0; sc[tid][1] += v1;
            sc[tid][2] += v2; sc[tid][3] += v3;
        }
        __syncthreads();
    }
    const int t0 = sc[255][0], t1 = sc[255][1], t2 = sc[255][2], t3 = sc[255][3];
    if (tid == 0) { cnt[0] = t0; cnt[1] = t1; cnt[2] = t2; cnt[3] = t3; }
    const int b1 = (t0 + 127) & ~127;
    const int b2 = b1 + ((t1 + 127) & ~127);
    const int b3 = b2 + ((t2 + 127) & ~127);
    int r0 = sc[tid][0] - l0;
    int r1 = b1 + sc[tid][1] - l1;
    int r2 = b2 + sc[tid][2] - l2;
    int r3 = b3 + sc[tid][3] - l3;
    #pragma unroll
    for (int i = 0; i < 8; i++) {
        const int t = tid * 8 + i;
        const int a = ep[i] & 15, b = (ep[i] >> 4) & 15;
        const int ra = (a == 0) ? r0++ : (a == 1) ? r1++ : (a == 2) ? r2++ : r3++;
        rowtok[ra] = t; tok2row[t * 2] = ra;
        const int rb = (b == 0) ? r0++ : (b == 1) ? r1++ : (b == 2) ? r2++ : r3++;
        rowtok[rb] = t; tok2row[t * 2 + 1] = rb;
    }
}

// ---------------------------------------------------------------------------
// bf16 MFMA GEMM: C[M,N] = A[M,K] * Bt[N,K]^T. 128x128 tile, 4 waves, BK=64.
// DB=1: double-buffered LDS (64 KB) with counted-wait prefetch loop:
//   STAGE(buf0); loop { vmcnt(0); barrier; STAGE(buf^1,next); MFMA(buf); }
//   -> next tile's global_load_lds latency hides under current compute.
//   Used for grid-starved dispatches (QKV 288 blocks, Wo 384 blocks).
// DB=0: single buffer, 2-barrier loop (FF1/FF2: >=3 resident blocks/CU
//   provide implicit overlap; 64 KB LDS would cut them to 2 - m132 trap).
// Staging swizzle: col group (lane&7)^(row&7) on the GLOBAL source side,
// mirrored on fragment reads -> conflict-free b128 (LDS dest stays linear).
// modes:
//  0 QKV: LDS-repacked epilogue. Q/K: uint4 row stores into [B,H,T,64].
//         V: transposed through LDS -> 16B stores along t into VT [B,H,64,T]
//         (lane pairs form 32B contiguous runs; was 2B/lane scatter).
//  2 FF1 (COMPACT): gathered A-rows; relu+comb scale; LDS-repacked stores
//  3 Wo split-K partial: fp32 -> outF + z*cZ
//  4 FF2 (COMPACT): per-expert slab, k-slice z; fp32 partials at compact rows
// swz: 0 = 3D grid; 1 = FF1 XCD map; 2 = QKV XCD-chunked flat 288;
//      3 = FF2 XCD map
// ---------------------------------------------------------------------------
template<int DB>
__global__ __launch_bounds__(256) void gemm_bt_kernel(
    const u16* __restrict__ A, int lda, long aZ,
    const u16* __restrict__ Bt, int ldb, long bZ,
    int K, int mode, int swz,
    float* __restrict__ outF, u16* __restrict__ outH,
    u16* __restrict__ outH2, u16* __restrict__ outH3,
    int ldc, long cZ,
    const float* __restrict__ biasF, int biasZ,
    const int* __restrict__ rowtok, const int* __restrict__ cntp,
    const float* __restrict__ comb)
{
    __shared__ __align__(16) u16 As[(DB ? 2 : 1) * 128 * 64];
    __shared__ __align__(16) u16 Bs[(DB ? 2 : 1) * 128 * 64];
    const int tid = threadIdx.x;
    int bx, by, z, e = 0, baseE = 0;
    if (swz == 3) {
        const int fid = blockIdx.x;
        const int xcd = fid & 7; int r = fid >> 3;
        const int half = (r >= 96) ? 1 : 0; r -= half * 96;
        bx = r % 6; by = r / 6;
        const int ez = xcd * 2 + half; e = ez >> 2; z = ez & 3;
    } else if (swz == 1) {
        const int fid = blockIdx.x;
        const int xcd = fid & 7; const int r = fid >> 3;
        const int ne = xcd * 12 + (r % 12);
        by = r / 12; bx = ne % 24; e = ne / 24; z = e;
    } else if (swz == 2) {
        // QKV flat 288: each XCD owns 36 consecutive (bx,by) blocks (by-major)
        const int fid = blockIdx.x;
        const int g = (fid & 7) * 36 + (fid >> 3);
        by = g & 15; bx = g >> 4; z = 0;
    } else {
        bx = blockIdx.x; by = blockIdx.y; z = blockIdx.z;
    }
    if (mode == 2 || mode == 4) {
        const int q0 = (cntp[0] + 127) & ~127;
        const int q1 = (cntp[1] + 127) & ~127;
        const int q2 = (cntp[2] + 127) & ~127;
        baseE = (e > 0 ? q0 : 0) + (e > 1 ? q1 : 0) + (e > 2 ? q2 : 0);
        if (by * 128 >= cntp[e]) return;   // uniform per block: safe early-exit
    }
    const int m0 = by * 128, n0 = bx * 128;
    const u16* Ab = A + (size_t)z * aZ;
    const u16* Bb = Bt + (size_t)z * bZ;
    if (mode == 4) {
        Ab += (size_t)baseE * lda;
        Bb += (size_t)e * ((size_t)DD * FFD);
    }

    const int wave = tid >> 6, lane = tid & 63;
    const int wm = (wave & 1) * 64, wn = (wave >> 1) * 64;
    const int fm = lane & 15;
    const int g  = lane >> 4;

    // staging: wave w covers tile rows [w*32, w*32+32); 4 instrs per operand,
    // instr i covers rows +[i*8, i*8+8). XOR col-group swizzle on global side.
    const int lr8 = lane >> 3;
    const int cg  = ((lane & 7) ^ lr8) * 8;   // swizzled global col (u16)
    const u16 *aG[4], *bG[4];
    u16 *aL[4], *bL[4];
    #pragma unroll
    for (int i = 0; i < 4; i++) {
        const int rr = wave * 32 + i * 8 + lr8;
        int arow;
        if (mode == 2) arow = rowtok[baseE + m0 + rr];
        else           arow = m0 + rr;
        aG[i] = Ab + (size_t)arow * lda + cg;
        bG[i] = Bb + (size_t)(n0 + rr) * ldb + cg;
        aL[i] = &As[(wave * 32 + i * 8) * 64];
        bL[i] = &Bs[(wave * 32 + i * 8) * 64];
    }

#define STAGE(B, KO) do {                                                      \
        const int _o = (B) * (128 * 64);                                       \
        _Pragma("unroll")                                                      \
        for (int _i = 0; _i < 4; _i++) ASYNC16(aG[_i] + (KO), aL[_i] + _o);    \
        _Pragma("unroll")                                                      \
        for (int _i = 0; _i < 4; _i++) ASYNC16(bG[_i] + (KO), bL[_i] + _o);    \
    } while (0)

    // fragment reads: global col g*8 + ks*32 lives at LDS group
    // ((g + ks*4) ^ (row&7)); row&7 == fm&7 for rows wm+i*16+fm
    const int c0 = ((g    ) ^ (fm & 7)) * 8;
    const int c1 = ((g + 4) ^ (fm & 7)) * 8;
    const u16* pa[4]; const u16* pb[4];
    #pragma unroll
    for (int i = 0; i < 4; i++) {
        pa[i] = &As[(wm + i * 16 + fm) * 64];
        pb[i] = &Bs[(wn + i * 16 + fm) * 64];
    }

    f32x4 acc[4][4] = {};
    int buf = 0;
    if (DB) STAGE(0, 0);

    for (int k0 = 0; k0 < K; k0 += 64) {
        if (DB) {
            asm volatile("s_waitcnt vmcnt(0)" ::: "memory");
            __builtin_amdgcn_s_barrier();
            __builtin_amdgcn_sched_barrier(0);
            if (k0 + 64 < K) STAGE(buf ^ 1, k0 + 64);
        } else {
            STAGE(0, k0);
            __syncthreads();
        }
        const int bo = DB ? buf * (128 * 64) : 0;
        #pragma unroll
        for (int ks = 0; ks < 2; ks++) {
            const int cc = bo + (ks ? c1 : c0);
            bf16x8 af[4], bf[4];
            #pragma unroll
            for (int i = 0; i < 4; i++)
                af[i] = *reinterpret_cast<const bf16x8*>(pa[i] + cc);
            #pragma unroll
            for (int j = 0; j < 4; j++)
                bf[j] = *reinterpret_cast<const bf16x8*>(pb[j] + cc);
            #pragma unroll
            for (int i = 0; i < 4; i++)
                #pragma unroll
                for (int j = 0; j < 4; j++)
                    acc[i][j] = MFMA16(af[i], bf[j], acc[i][j]);
        }
        if (DB) buf ^= 1;
        else    __syncthreads();
    }
    if (DB) __syncthreads();
#undef STAGE

    // C/D layout: col = lane&15, row = (lane>>4)*4 + reg   [m89-verified]
    const int cn = lane & 15, cr = (lane >> 4) * 4;

    if (mode == 0) {
        // LDS-repacked epilogue, 4 passes x 32 rows (rows i*16+[0,16) at
        // wm=0 -> Cs rows 0-15; wm=64 -> Cs rows 16-31).
        const int which = (n0 >= 1536) ? 2 : (n0 >= 768 ? 1 : 0);
        const int nb = n0 - which * 768;
        u16* outP = (which == 0) ? outH : (which == 1) ? outH2 : outH3;
        u16* Cs = As;
        #pragma unroll
        for (int i = 0; i < 4; i++) {
            if (i) __syncthreads();
            #pragma unroll
            for (int j = 0; j < 4; j++) {
                const int n = n0 + wn + j * 16 + cn;
                const float bias = biasF[n];
                #pragma unroll
                for (int r = 0; r < 4; r++) {
                    Cs[((wave & 1) * 16 + cr + r) * 128 + wn + j * 16 + cn] =
                        f2us(acc[i][j][r] + bias);
                }
            }
            __syncthreads();
            if (which < 2) {
                // Q/K: row stores, 16 u16 per thread within one head's 64-run
                const int lr2 = tid >> 3, c2 = (tid & 7) * 16;
                const int m2 = m0 + (lr2 >> 4) * 64 + i * 16 + (lr2 & 15);
                const int bb2 = m2 >> 10, t2 = m2 & 1023;
                const int hh = (nb + c2) >> 6, d0 = (nb + c2) & 63;
                u16* dst = outP + (((size_t)(bb2 * HH + hh) * TT + t2) << 6) + d0;
                *reinterpret_cast<uint4*>(dst) =
                    *reinterpret_cast<const uint4*>(&Cs[lr2 * 128 + c2]);
                *reinterpret_cast<uint4*>(dst + 8) =
                    *reinterpret_cast<const uint4*>(&Cs[lr2 * 128 + c2 + 8]);
            } else {
                // V: transpose through LDS; thread gathers 8 m for one d,
                // stores 16B along t (lane pairs -> 32B contiguous).
                const int nl = tid >> 1, half = tid & 1;
                const int hh = (nb + nl) >> 6, d = (nb + nl) & 63;
                #pragma unroll
                for (int seg = 0; seg < 2; seg++) {
                    u16 o[8];
                    #pragma unroll
                    for (int k = 0; k < 8; k++)
                        o[k] = Cs[(seg * 16 + half * 8 + k) * 128 + nl];
                    const int t0 = m0 + seg * 64 + i * 16 + half * 8;
                    const int bb2 = t0 >> 10, tt2 = t0 & 1023;
                    u16* dst = outP + (((size_t)(bb2 * HH + hh) * HD + d) << 10) + tt2;
                    *reinterpret_cast<uint4*>(dst) = *reinterpret_cast<uint4*>(o);
                }
            }
        }
        return;
    }

    if (mode == 2) {
        // LDS-repacked epilogue: 4 passes x 32 rows, dwordx4 coalesced stores
        u16* Cs = As;
        #pragma unroll
        for (int i = 0; i < 4; i++) {
            if (i) __syncthreads();
            int tokr[4]; float combr[4];
            #pragma unroll
            for (int r = 0; r < 4; r++)
                tokr[r] = rowtok[baseE + m0 + wm + i * 16 + cr + r];
            #pragma unroll
            for (int r = 0; r < 4; r++)
                combr[r] = comb[(size_t)tokr[r] * NE + z];
            #pragma unroll
            for (int j = 0; j < 4; j++) {
                const int n = n0 + wn + j * 16 + cn;
                const float bias = biasF[(size_t)z * biasZ + n];
                #pragma unroll
                for (int r = 0; r < 4; r++) {
                    float y = fmaxf(acc[i][j][r] + bias, 0.f) * combr[r];
                    Cs[((wave & 1) * 16 + cr + r) * 128 + wn + j * 16 + cn] = f2us(y);
                }
            }
            __syncthreads();
            const int lr2 = tid >> 3, c2 = (tid & 7) * 16;
            const int m2 = m0 + (lr2 >> 4) * 64 + i * 16 + (lr2 & 15);
            u16* dst = outH + (size_t)(baseE + m2) * ldc + n0 + c2;
            *reinterpret_cast<uint4*>(dst) =
                *reinterpret_cast<const uint4*>(&Cs[lr2 * 128 + c2]);
            *reinterpret_cast<uint4*>(dst + 8) =
                *reinterpret_cast<const uint4*>(&Cs[lr2 * 128 + c2 + 8]);
        }
        return;
    }

    #pragma unroll
    for (int i = 0; i < 4; i++) {
        #pragma unroll
        for (int j = 0; j < 4; j++) {
            const int n = n0 + wn + j * 16 + cn;
            #pragma unroll
            for (int r = 0; r < 4; r++) {
                const int m = m0 + wm + i * 16 + cr + r;
                // mode 3 (baseE=0) and mode 4 (compact rows)
                float* basep = outF + (size_t)z * cZ;
                basep[(size_t)(baseE + m) * ldc + n] = acc[i][j][r];
            }
        }
    }
}

// ---------------------------------------------------------------------------
// MFMA attention. Block = (qt 32 rows, b*12+h). 4 waves.
// ---------------------------------------------------------------------------
#define PSTR 1032  // u16 stride: byte stride 2064 (16B aligned), dw 516 ≡ 4 mod 8 -> conflict-free b128
__global__ __launch_bounds__(256, 2) void attn_mfma_kernel(
    const u16* __restrict__ Qh, const u16* __restrict__ Kh,
    const u16* __restrict__ VT, const float* __restrict__ gamma_p,
    u16* __restrict__ attn_out)
{
    __shared__ __align__(16) u16 P[32 * PSTR];
    __shared__ float wred[4][32][4];
    __shared__ float dred[4][32];
    __shared__ float aArr[32], cmArr[32], dinvArr[32];

    const int qt = blockIdx.x, bh = blockIdx.y;
    const int b = bh / HH, h = bh - b * HH;
    const int tid = threadIdx.x, wave = tid >> 6, lane = tid & 63;
    const int g = lane >> 4, fm = lane & 15;
    const float gamma = gamma_p[0];
    const int m0 = qt * 32;
    const u16* Qp = Qh + (size_t)bh * TT * HD;
    const u16* Kp = Kh + (size_t)bh * TT * HD;
    const u16* Vp = VT + (size_t)bh * HD * TT;

    bf16x8 af[2][2];
    #pragma unroll
    for (int mi = 0; mi < 2; mi++)
        #pragma unroll
        for (int ks = 0; ks < 2; ks++)
            af[mi][ks] = *reinterpret_cast<const bf16x8*>(
                Qp + (size_t)(m0 + mi * 16 + fm) * HD + ks * 32 + g * 8);

    const int n0w = wave * 256;
    f32x4 acc[16][2] = {};
    #pragma unroll
    for (int nj = 0; nj < 16; nj++) {
        const u16* kp = Kp + (size_t)(n0w + nj * 16 + fm) * HD + g * 8;
        bf16x8 b0 = *reinterpret_cast<const bf16x8*>(kp);
        bf16x8 b1 = *reinterpret_cast<const bf16x8*>(kp + 32);
        acc[nj][0] = MFMA16(af[0][0], b0, acc[nj][0]);
        acc[nj][0] = MFMA16(af[0][1], b1, acc[nj][0]);
        acc[nj][1] = MFMA16(af[1][0], b0, acc[nj][1]);
        acc[nj][1] = MFMA16(af[1][1], b1, acc[nj][1]);
    }

    #pragma unroll
    for (int mi = 0; mi < 2; mi++) {
        #pragma unroll
        for (int r = 0; r < 4; r++) {
            float s1 = 0.f, s2 = 0.f, mx = -3.4e38f, mn = 3.4e38f;
            #pragma unroll
            for (int nj = 0; nj < 16; nj++) {
                float v = acc[nj][mi][r];
                s1 += v; s2 = fmaf(v, v, s2);
                mx = fmaxf(mx, v); mn = fminf(mn, v);
            }
            #pragma unroll
            for (int msk = 1; msk < 16; msk <<= 1) {
                s1 += __shfl_xor(s1, msk);
                s2 += __shfl_xor(s2, msk);
                mx = fmaxf(mx, __shfl_xor(mx, msk));
                mn = fminf(mn, __shfl_xor(mn, msk));
            }
            if (fm == 0) {
                int row = mi * 16 + g * 4 + r;
                wred[wave][row][0] = s1; wred[wave][row][1] = s2;
                wred[wave][row][2] = mx; wred[wave][row][3] = mn;
            }
        }
    }
    __syncthreads();
    if (tid < 32) {
        float s1 = 0.f, s2 = 0.f, mx = -3.4e38f, mn = 3.4e38f;
        #pragma unroll
        for (int w = 0; w < 4; w++) {
            s1 += wred[w][tid][0]; s2 += wred[w][tid][1];
            mx = fmaxf(mx, wred[w][tid][2]); mn = fminf(mn, wred[w][tid][3]);
        }
        float var = (s2 - s1 * s1 * (1.f / TT)) * (1.f / (TT - 1));
        var = fmaxf(var, 0.f);
        float a = gamma / (sqrtf(var) + 8e-5f);
        aArr[tid] = a;
        cmArr[tid] = (a >= 0.f) ? a * mx : a * mn;
    }
    __syncthreads();

    #pragma unroll
    for (int mi = 0; mi < 2; mi++) {
        #pragma unroll
        for (int r = 0; r < 4; r++) {
            const int row = mi * 16 + g * 4 + r;
            const float a = aArr[row], cm = cmArr[row];
            float dp = 0.f;
            #pragma unroll
            for (int nj = 0; nj < 16; nj++) {
                float p = __expf(fmaf(a, acc[nj][mi][r], -cm));
                u16 pb = f2us(p);
                dp += us2f(pb);
                P[row * PSTR + n0w + nj * 16 + fm] = pb;
            }
            #pragma unroll
            for (int msk = 1; msk < 16; msk <<= 1) dp += __shfl_xor(dp, msk);
            if (fm == 0) dred[wave][row] = dp;
        }
    }
    __syncthreads();
    if (tid < 32)
        dinvArr[tid] = 1.f / (dred[0][tid] + dred[1][tid] + dred[2][tid] + dred[3][tid]);
    __syncthreads();

    f32x4 oacc[2] = {};
    #pragma unroll 4
    for (int ks = 0; ks < 32; ks++) {
        bf16x8 bv = *reinterpret_cast<const bf16x8*>(
            Vp + (size_t)(wave * 16 + fm) * TT + ks * 32 + g * 8);
        bf16x8 a0 = *reinterpret_cast<const bf16x8*>(&P[(size_t)fm * PSTR + ks * 32 + g * 8]);
        bf16x8 a1 = *reinterpret_cast<const bf16x8*>(&P[(size_t)(16 + fm) * PSTR + ks * 32 + g * 8]);
        oacc[0] = MFMA16(a0, bv, oacc[0]);
        oacc[1] = MFMA16(a1, bv, oacc[1]);
    }
    #pragma unroll
    for (int mi = 0; mi < 2; mi++) {
        #pragma unroll
        for (int r = 0; r < 4; r++) {
            int row = mi * 16 + g * 4 + r;
            int t = m0 + row;
            attn_out[((size_t)(b * TT + t)) * DD + h * HD + wave * 16 + fm] =
                f2us(oacc[mi][r] * dinvArr[row]);
        }
    }
}

// ---------------------------------------------------------------------------
// LN1 fused + gate: layernorm -> x fp32 + xh bf16; gate on in-register
// post-LN values; thread-0 softmax/top-2 -> comb, epack.
// ---------------------------------------------------------------------------
__global__ __launch_bounds__(256) void ln1_kernel(
    const float* __restrict__ p0, const float* __restrict__ p1,
    const float* __restrict__ p2, const float* __restrict__ p3,
    const float* __restrict__ src, const float* __restrict__ bo,
    const float* __restrict__ g, const float* __restrict__ bta,
    const float* __restrict__ Wg, const float* __restrict__ bg,
    float* __restrict__ outF, u16* __restrict__ outH,
    float* __restrict__ comb, int* __restrict__ epack)
{
    const int row = blockIdx.x, tid = threadIdx.x;
    __shared__ float red[256];
    __shared__ float gred[4][4];
    const size_t base = (size_t)row * DD;
    float v[3];
    #pragma unroll
    for (int i = 0; i < 3; i++) {
        int c = tid + i * 256;
        v[i] = p0[base + c] + p1[base + c] + p2[base + c] + p3[base + c]
             + src[base + c] + bo[c];
    }
    float s = v[0] + v[1] + v[2];
    red[tid] = s; __syncthreads();
    #pragma unroll
    for (int o = 128; o > 0; o >>= 1) { if (tid < o) red[tid] += red[tid + o]; __syncthreads(); }
    const float mean = red[0] * (1.f / 768.f);
    __syncthreads();
    float qv = 0.f;
    #pragma unroll
    for (int i = 0; i < 3; i++) { float d = v[i] - mean; qv += d * d; }
    red[tid] = qv; __syncthreads();
    #pragma unroll
    for (int o = 128; o > 0; o >>= 1) { if (tid < o) red[tid] += red[tid + o]; __syncthreads(); }
    const float var = red[0] * (1.f / 768.f);
    const float rs = rsqrtf(var + 1e-5f);
    float ga0 = 0.f, ga1 = 0.f, ga2 = 0.f, ga3 = 0.f;
    #pragma unroll
    for (int i = 0; i < 3; i++) {
        int c = tid + i * 256;
        float o = (v[i] - mean) * rs * g[c] + bta[c];
        outF[base + c] = o;
        outH[base + c] = f2us(o);
        ga0 = fmaf(o, Wg[c], ga0);
        ga1 = fmaf(o, Wg[DD + c], ga1);
        ga2 = fmaf(o, Wg[2 * DD + c], ga2);
        ga3 = fmaf(o, Wg[3 * DD + c], ga3);
    }
    #pragma unroll
    for (int off = 32; off > 0; off >>= 1) {
        ga0 += __shfl_down(ga0, off, 64);
        ga1 += __shfl_down(ga1, off, 64);
        ga2 += __shfl_down(ga2, off, 64);
        ga3 += __shfl_down(ga3, off, 64);
    }
    const int wave = tid >> 6, lane = tid & 63;
    if (lane == 0) {
        gred[wave][0] = ga0; gred[wave][1] = ga1;
        gred[wave][2] = ga2; gred[wave][3] = ga3;
    }
    __syncthreads();
    if (tid == 0) {
        float gg[NE];
        #pragma unroll
        for (int e = 0; e < NE; e++)
            gg[e] = gred[0][e] + gred[1][e] + gred[2][e] + gred[3][e] + bg[e];
        float m = -1e30f;
        #pragma unroll
        for (int e = 0; e < NE; e++) m = fmaxf(m, gg[e]);
        float ex[NE], ssum = 0.f;
        #pragma unroll
        for (int e = 0; e < NE; e++) { ex[e] = __expf(gg[e] - m); ssum += ex[e]; }
        #pragma unroll
        for (int e = 0; e < NE; e++) ex[e] /= ssum;
        int e1 = 0;
        #pragma unroll
        for (int e = 1; e < NE; e++) if (ex[e] > ex[e1]) e1 = e;
        int e2 = -1;
        #pragma unroll
        for (int e = 0; e < NE; e++) if (e != e1 && (e2 < 0 || ex[e] > ex[e2])) e2 = e;
        float c[NE] = {0.f, 0.f, 0.f, 0.f};
        c[e1] = ex[e1]; c[e2] = ex[e2];
        #pragma unroll
        for (int e = 0; e < NE; e++) comb[(size_t)row * NE + e] = c[e];
        epack[row] = e1 | (e2 << 4);
    }
}

// ---------------------------------------------------------------------------
// LN2 (compact): t = x + sum_z sum_{i=0,1} pslab[z][tok2row[t,i]] + comb*b2;
// layernorm -> out.
// ---------------------------------------------------------------------------
__global__ __launch_bounds__(256) void ln2_kernel(
    const float* __restrict__ x, const float* __restrict__ pslab,
    const int* __restrict__ tok2row,
    const float* __restrict__ comb, const float* __restrict__ b2,
    const float* __restrict__ g, const float* __restrict__ bta,
    float* __restrict__ outF)
{
    const int row = blockIdx.x, tid = threadIdx.x;
    __shared__ float red[256];
    const size_t base = (size_t)row * DD;
    const int r0 = tok2row[row * 2], r1 = tok2row[row * 2 + 1];
    const float* q0 = pslab + (size_t)r0 * DD;
    const float* q1 = pslab + (size_t)r1 * DD;
    const float c0 = comb[row * NE + 0], c1 = comb[row * NE + 1];
    const float c2 = comb[row * NE + 2], c3 = comb[row * NE + 3];
    float v[3];
    #pragma unroll
    for (int i = 0; i < 3; i++) {
        int c = tid + i * 256;
        float t = x[base + c];
        t += q0[c] + q0[SLABZ + c] + q0[2 * SLABZ + c] + q0[3 * SLABZ + c];
        t += q1[c] + q1[SLABZ + c] + q1[2 * SLABZ + c] + q1[3 * SLABZ + c];
        t = fmaf(c0, b2[c], t);
        t = fmaf(c1, b2[DD + c], t);
        t = fmaf(c2, b2[2 * DD + c], t);
        t = fmaf(c3, b2[3 * DD + c], t);
        v[i] = t;
    }
    float s = v[0] + v[1] + v[2];
    red[tid] = s; __syncthreads();
    #pragma unroll
    for (int o = 128; o > 0; o >>= 1) { if (tid < o) red[tid] += red[tid + o]; __syncthreads(); }
    const float mean = red[0] * (1.f / 768.f);
    __syncthreads();
    float qv = 0.f;
    #pragma unroll
    for (int i = 0; i < 3; i++) { float d = v[i] - mean; qv += d * d; }
    red[tid] = qv; __syncthreads();
    #pragma unroll
    for (int o = 128; o > 0; o >>= 1) { if (tid < o) red[tid] += red[tid + o]; __syncthreads(); }
    const float var = red[0] * (1.f / 768.f);
    const float rs = rsqrtf(var + 1e-5f);
    #pragma unroll
    for (int i = 0; i < 3; i++) {
        int c = tid + i * 256;
        outF[base + c] = (v[i] - mean) * rs * g[c] + bta[c];
    }
}

extern "C" void kernel_launch(void* const* d_in, const int* in_sizes, int n_in,
                              void* d_out, int out_size, void* d_ws, size_t ws_size,
                              hipStream_t stream)
{
    const float* src  = (const float*)d_in[0];
    const float* Wq   = (const float*)d_in[2];  const float* bq = (const float*)d_in[3];
    const float* Wk   = (const float*)d_in[4];  const float* bk = (const float*)d_in[5];
    const float* Wv   = (const float*)d_in[6];  const float* bv = (const float*)d_in[7];
    const float* Wo   = (const float*)d_in[8];  const float* bo = (const float*)d_in[9];
    const float* gam  = (const float*)d_in[10];
    const float* ln1g = (const float*)d_in[11]; const float* ln1b = (const float*)d_in[12];
    const float* ln2g = (const float*)d_in[13]; const float* ln2b = (const float*)d_in[14];
    const float* Wg   = (const float*)d_in[15]; const float* bg = (const float*)d_in[16];
    const float* W1   = (const float*)d_in[17]; const float* b1 = (const float*)d_in[18];
    const float* W2   = (const float*)d_in[19]; const float* b2 = (const float*)d_in[20];
    (void)ws_size; (void)in_sizes; (void)n_in; (void)out_size;

    char* ws = (char*)d_ws;
    u16*   W1T  = (u16*)(ws);
    float* wop  = (float*)(ws + 18874368);
    float* pslab= (float*)(ws);
    u16*   W2T  = (u16*)(ws + 56623104);               // 18,874,368 (live through FF2)
    u16*   hb   = (u16*)(ws + 75497472);               // 28,311,552 compact FF1 out [CROWS][3072]
    float* x    = (float*)(ws + 103809024);            //  6,291,456
    u16*   xh   = (u16*)(ws + 110100480);              //  3,145,728
    float* comb = (float*)(ws + 113246208);            //     32,768
    float* bqkv = (float*)(ws + 113278976);            //      9,216
    int*   cnt    = (int*)(ws + 113288192);            //         64
    int*   rowtok = (int*)(ws + 113288256);            //     18,432 (CROWS)
    int*   epack  = (int*)(ws + 113306688);            //      8,192
    int*   tok2row= (int*)(ws + 113323072);            //     16,384
    // attn-phase aliases inside hb region (all dead before FF1 writes hb)
    char* H = ws + 75497472;
    u16*   Qh     = (u16*)(H);
    u16*   Kh     = (u16*)(H + 3145728);
    u16*   VTh    = (u16*)(H + 6291456);
    u16*   src_h  = (u16*)(H + 9437184);
    u16*   attn_h = (u16*)(H + 12582912);
    u16*   WqkvH  = (u16*)(H + 15728640);
    u16*   WoH    = (u16*)(H + 19267584);
    const long PZ = (long)NTOK * DD;

    // ---- fused conversions (1 launch: src + 4 weights + 3 biases) ----
    convert5_kernel<<<1921, 256, 0, stream>>>(
        src, Wq, Wk, Wv, Wo, bq, bk, bv, src_h, WqkvH, WoH, bqkv);
    transpose_convert_kernel<<<dim3(FFD / 32, DD / 32, NE), 256, 0, stream>>>(
        W1, W1T, FFD, DD, (long)DD * FFD, (long)FFD * DD);
    transpose_convert_kernel<<<dim3(DD / 32, FFD / 32, NE), 256, 0, stream>>>(
        W2, W2T, DD, FFD, (long)FFD * DD, (long)FFD * DD);

    // ---- QKV (dbuf prefetch, XCD-chunked flat 288) ----
    gemm_bt_kernel<1><<<dim3(288, 1, 1), 256, 0, stream>>>(
        src_h, DD, 0, WqkvH, DD, 0, DD, 0, 2,
        nullptr, Qh, Kh, VTh, 0, 0, bqkv, 0, nullptr, nullptr, nullptr);

    // ---- attention (MFMA) ----
    attn_mfma_kernel<<<dim3(TT / 32, BB * HH), 256, 0, stream>>>(
        Qh, Kh, VTh, gam, attn_h);

    // ---- Wo projection split-K x4 (dbuf prefetch) -> fp32 partials ----
    gemm_bt_kernel<1><<<dim3(DD / 128, NTOK / 128, 4), 256, 0, stream>>>(
        attn_h, DD, 192L, WoH, DD, 192L, 192, 3, 0,
        wop, nullptr, nullptr, nullptr, DD, PZ, nullptr, 0, nullptr, nullptr, nullptr);

    // ---- LN1 + fused gate (no atomics) ----
    ln1_kernel<<<NTOK, 256, 0, stream>>>(
        wop, wop + PZ, wop + 2 * PZ, wop + 3 * PZ, src, bo,
        ln1g, ln1b, Wg, bg, x, xh, comb, epack);

    // ---- deterministic slot assignment (single-block prefix scan) ----
    scan_build_kernel<<<1, 256, 0, stream>>>(epack, cnt, rowtok, tok2row);

    // ---- FF1 compact (top-2 only), single-buffer (occupancy) ----
    gemm_bt_kernel<0><<<dim3(1536, 1, 1), 256, 0, stream>>>(
        xh, DD, 0, W1T, DD, (long)FFD * DD, DD, 2, 1,
        nullptr, hb, nullptr, nullptr, FFD, 0, b1, FFD, rowtok, cnt, comb);

    // ---- FF2 compact: per-expert K=3072 split-K x4, single-buffer ----
    gemm_bt_kernel<0><<<dim3(1536, 1, 1), 256, 0, stream>>>(
        hb, FFD, 768L, W2T, FFD, 768L, 768, 4, 3,
        pslab, nullptr, nullptr, nullptr, DD, SLABZ, nullptr, 0, rowtok, cnt, nullptr);

    // ---- LN2 (x + gathered compact partials + comb*b2, then layernorm) ----
    ln2_kernel<<<NTOK, 256, 0, stream>>>(
        x, pslab, tok2row, comb, b2, ln2g, ln2b, (float*)d_out);
}